// Round 6
// baseline (2043.253 us; speedup 1.0000x reference)
//
#include <hip/hip_runtime.h>
#include <hip/hip_bf16.h>

#define NN 50000
#define NE 1000000
#define NG 256
#define NL 6
#define NB_SCAN 196   // ceil(NN/256)
#define EB 128        // edges per block in k_edge2
#define TSTR 66       // bf16 stride per LDS row in k_edge2 (132 B; conflict-free)

typedef float v2f __attribute__((ext_vector_type(2)));
typedef short short8 __attribute__((ext_vector_type(8)));   // 8 bf16 (4 VGPRs) MFMA frag
typedef float f32x4 __attribute__((ext_vector_type(4)));    // MFMA accum

#define MFMA_BF16(a,b,c) __builtin_amdgcn_mfma_f32_16x16x32_bf16(a,b,c,0,0,0)

// silu via hardware rcp (v_rcp_f32, ~1e-7 rel err)
__device__ __forceinline__ float siluf(float v){
  return v * __builtin_amdgcn_rcpf(1.0f + __expf(-v));
}

// bf16 helpers (RNE — used for WEIGHT prep only; activations use trunc-split below)
__device__ __forceinline__ unsigned f2bf(float x){
  unsigned u = __float_as_uint(x);
  return (u + 0x7FFFu + ((u>>16)&1u)) >> 16;
}
__device__ __forceinline__ float bf2f(unsigned h){
  return __uint_as_float(h<<16);
}

// pack hi16(a) | hi16(b)<<16 in ONE v_perm_b32
__device__ __forceinline__ unsigned pkhi(unsigned a, unsigned b){
  return __builtin_amdgcn_perm(b, a, 0x07060302u);
}
// trunc-split 4 values into packed bf16 hi pairs + lo (trunc of exact residual) pairs.
__device__ __forceinline__ void split4(float v0,float v1,float v2,float v3,
                                       unsigned &h01, unsigned &h23,
                                       unsigned &l01, unsigned &l23){
  unsigned u0=__float_as_uint(v0),u1=__float_as_uint(v1);
  unsigned u2=__float_as_uint(v2),u3=__float_as_uint(v3);
  h01=pkhi(u0,u1); h23=pkhi(u2,u3);
  float r0=v0-__uint_as_float(u0&0xFFFF0000u);
  float r1=v1-__uint_as_float(u1&0xFFFF0000u);
  float r2=v2-__uint_as_float(u2&0xFFFF0000u);
  float r3=v3-__uint_as_float(u3&0xFFFF0000u);
  l01=pkhi(__float_as_uint(r0),__float_as_uint(r1));
  l23=pkhi(__float_as_uint(r2),__float_as_uint(r3));
}

// ---- degree counts (dst + src) ----
__global__ void k_degrees(const int* __restrict__ ei, int* __restrict__ cnt_dst,
                          int* __restrict__ cnt_src){
  int e = blockIdx.x*256 + threadIdx.x;
  if (e<NE){
    atomicAdd(&cnt_dst[ei[NE+e]], 1);
    atomicAdd(&cnt_src[ei[e]], 1);
  }
}

// ---- hierarchical scan ----
__global__ void k_scan1(const int* __restrict__ cnt, int* __restrict__ roff,
                        int* __restrict__ bsum){
  __shared__ int sd[256];
  int t=threadIdx.x; int i=blockIdx.x*256+t;
  int v=(i<NN)?cnt[i]:0;
  sd[t]=v; __syncthreads();
  #pragma unroll
  for(int off=1;off<256;off<<=1){
    int xv=(t>=off)?sd[t-off]:0; __syncthreads();
    sd[t]+=xv; __syncthreads();
  }
  if(i<NN) roff[i]=sd[t]-v;
  if(t==255) bsum[blockIdx.x]=sd[t];
}
__global__ void k_scan2(const int* __restrict__ bsum, int* __restrict__ bbase,
                        int* __restrict__ roff){
  __shared__ int sd[256];
  int t=threadIdx.x;
  int v=(t<NB_SCAN)?bsum[t]:0;
  sd[t]=v; __syncthreads();
  #pragma unroll
  for(int off=1;off<256;off<<=1){
    int xv=(t>=off)?sd[t-off]:0; __syncthreads();
    sd[t]+=xv; __syncthreads();
  }
  if(t<NB_SCAN) bbase[t]=sd[t]-v;
  if(t==255) roff[NN]=sd[t];
}
__global__ void k_scan3(int* __restrict__ roff, const int* __restrict__ bbase){
  int i=blockIdx.x*256+threadIdx.x;
  if(i<NN) roff[i]+=bbase[blockIdx.x];
}

// ---- scatter-fill: dlist = edge ids dst-sorted; slist = dst-sorted POSITIONS per src ----
__global__ void k_fill(const int* __restrict__ ei,
                       const int* __restrict__ roff_dst, const int* __restrict__ roff_src,
                       int* __restrict__ cur_dst, int* __restrict__ cur_src,
                       int* __restrict__ dlist, int* __restrict__ slist){
  int e = blockIdx.x*256 + threadIdx.x;
  if (e<NE){
    int d = ei[NE+e];
    int pd = roff_dst[d] + atomicAdd(&cur_dst[d],1);
    dlist[pd] = e;
    int s = ei[e];
    int ps = roff_src[s] + atomicAdd(&cur_src[s],1);
    slist[ps] = pd;
  }
}

// ---- one-time gather into dst-sorted order + ef -> B-fragment bf16 hi/lo tiles ----
__global__ void k_gather(const int* __restrict__ ei, const float* __restrict__ ef,
                         const int* __restrict__ dlist,
                         int2* __restrict__ sd_s, unsigned short* __restrict__ efb){
  int p = blockIdx.x*256 + threadIdx.x;
  if (p<NE){
    int e = dlist[p];
    sd_s[p] = make_int2(ei[e], ei[NE+e]);
    int tile = p>>4, l15 = p&15;
    size_t hb = (size_t)tile*512 + (size_t)l15*8;
    const float4* src = (const float4*)(ef + (size_t)e*16);
    #pragma unroll
    for(int q=0;q<4;q++){
      float4 v = src[q];
      float vv[4] = {v.x, v.y, v.z, v.w};
      #pragma unroll
      for(int r=0;r<4;r++){
        int k = q*4+r;
        unsigned h  = f2bf(vv[r]);
        unsigned lo = f2bf(vv[r]-bf2f(h));
        size_t o = hb + (size_t)(k>>3)*128 + (k&7);
        efb[o]     = (unsigned short)h;
        efb[o+256] = (unsigned short)lo;
      }
    }
  }
}

// ---- init coords + 1/max(indeg,1) ----
__global__ void k_prep(const float* __restrict__ coords,
                       const int* __restrict__ cnt,
                       float* __restrict__ x, float* __restrict__ cntinv){
  int n = blockIdx.x*256+threadIdx.x;
  if (n<NN){
    x[n*3+0]=coords[n*3+0];
    x[n*3+1]=coords[n*3+1];
    x[n*3+2]=coords[n*3+2];
    cntinv[n]=1.0f/fmaxf((float)cnt[n],1.0f);
  }
}

// ---- one-time weight prep: edge-kernel blobs (RNE hi/lo) ----
__global__ void k_wprep(const float* __restrict__ w1full, const float* __restrict__ w2,
                        const float* __restrict__ xw1,
                        unsigned short* __restrict__ blob){
  int t = blockIdx.x*256 + threadIdx.x;
  if (t >= NL*40*64) return;
  int lane = t & 63;
  int f = (t>>6) % 40;
  int l = t / (40*64);
  int m, hl;
  unsigned short* out = blob + (size_t)t*8;
  if (f < 8){
    int mt = f>>1; hl = f&1;
    m = mt*16 + (lane&15);
    int kb = (lane>>4)*8;
    #pragma unroll
    for(int j=0;j<8;j++){
      int k = kb + j;
      float v = (k<16) ? w1full[(size_t)l*273*64 + (size_t)(257+k)*64 + m] : 0.f;
      unsigned h = f2bf(v);
      if (hl) h = f2bf(v - bf2f(h));
      out[j] = (unsigned short)h;
    }
  } else {
    int fi = (f<24) ? (f-8) : (f-24);
    const float* W = ((f<24) ? w2 : xw1) + (size_t)l*4096;
    int mt = fi>>2, kt = (fi>>1)&1; hl = fi&1;
    m = mt*16 + (lane&15);
    int kb = kt*32 + (lane>>4)*8;
    #pragma unroll
    for(int j=0;j<8;j++){
      float v = W[(size_t)(kb+j)*64 + m];
      unsigned h = f2bf(v);
      if (hl) h = f2bf(v - bf2f(h));
      out[j] = (unsigned short)h;
    }
  }
}

// ---- one-time weight prep: node-side blobs (RNE hi/lo) ----
__global__ void k_wprep2(const float* __restrict__ pw1, const float* __restrict__ hw1,
                         const float* __restrict__ hw2, unsigned short* __restrict__ blob){
  int t = blockIdx.x*256 + threadIdx.x;
  if (t >= NL*224*64) return;
  int lane = t & 63;
  int f = (t>>6) % 224;
  int l = t / (224*64);
  int m15 = lane & 15, kq = (lane>>4)*8;
  unsigned short* out = blob + (size_t)t*8;
  if (f < 64){
    int mt = f>>3, kt = (f>>1)&3, hl = f&1;
    int m = mt*16 + m15;
    const float* W = pw1 + (size_t)l*273*64;
    #pragma unroll
    for(int j=0;j<8;j++){
      int k = kt*32 + kq + j;
      float v = (m<64) ? W[(size_t)k*64 + m] : W[(size_t)(128+k)*64 + (m-64)];
      unsigned hb = f2bf(v);
      if (hl) hb = f2bf(v - bf2f(hb));
      out[j] = (unsigned short)hb;
    }
  } else if (f < 160){
    int fi = f - 64;
    int mt = fi/12, r = fi%12, kt = r>>1, hl = r&1;
    int m = mt*16 + m15;
    const float* W = hw1 + (size_t)l*192*128;
    #pragma unroll
    for(int j=0;j<8;j++){
      int k = kt*32 + kq + j;
      float v = W[(size_t)k*128 + m];
      unsigned hb = f2bf(v);
      if (hl) hb = f2bf(v - bf2f(hb));
      out[j] = (unsigned short)hb;
    }
  } else {
    int fi = f - 160;
    int mt = fi>>3, kt = (fi>>1)&3, hl = fi&1;
    int m = mt*16 + m15;
    const float* W = hw2 + (size_t)l*128*128;
    #pragma unroll
    for(int j=0;j<8;j++){
      int k = kt*32 + kq + j;
      float v = W[(size_t)k*128 + m];
      unsigned hb = f2bf(v);
      if (hl) hb = f2bf(v - bf2f(hb));
      out[j] = (unsigned short)hb;
    }
  }
}

// ==== tiled encoder (unchanged) ====
__global__ void __launch_bounds__(256)
k_encoder(const float* __restrict__ nf,
          const float* __restrict__ w1, const float* __restrict__ b1,
          const float* __restrict__ w2, const float* __restrict__ b2,
          float* __restrict__ h){
  __shared__ float in1[32][17];
  __shared__ float t1[32][129];
  __shared__ float wt[16][136];
  int tid=threadIdx.x;
  int g0=blockIdx.x*32;
  int ty=tid>>4, tx=tid&15;
  int n0=ty*2, n1=ty*2+1;
  { int n=tid>>3, c=(tid&7)*2;
    int gn=g0+n; if(gn>=NN) gn=NN-1;
    float2 v=*(const float2*)(nf+(size_t)gn*16+c);
    in1[n][c]=v.x; in1[n][c+1]=v.y; }
  { int c=tx*8;
    const float* src=w1+(size_t)ty*128+c;
    *(float4*)&wt[ty][c]  =*(const float4*)src;
    *(float4*)&wt[ty][c+4]=*(const float4*)(src+4); }
  __syncthreads();
  float4 a00,a01,a10,a11;
  a00=*(const float4*)(b1+tx*8); a01=*(const float4*)(b1+tx*8+4);
  a10=a00; a11=a01;
  #pragma unroll
  for(int k=0;k<16;k++){
    float m0=in1[n0][k], m1=in1[n1][k];
    float4 wa=*(float4*)&wt[k][tx*8], wb=*(float4*)&wt[k][tx*8+4];
    a00.x+=m0*wa.x; a00.y+=m0*wa.y; a00.z+=m0*wa.z; a00.w+=m0*wa.w;
    a01.x+=m0*wb.x; a01.y+=m0*wb.y; a01.z+=m0*wb.z; a01.w+=m0*wb.w;
    a10.x+=m1*wa.x; a10.y+=m1*wa.y; a10.z+=m1*wa.z; a10.w+=m1*wa.w;
    a11.x+=m1*wb.x; a11.y+=m1*wb.y; a11.z+=m1*wb.z; a11.w+=m1*wb.w;
  }
  int c8=tx*8;
  t1[n0][c8+0]=siluf(a00.x); t1[n0][c8+1]=siluf(a00.y); t1[n0][c8+2]=siluf(a00.z); t1[n0][c8+3]=siluf(a00.w);
  t1[n0][c8+4]=siluf(a01.x); t1[n0][c8+5]=siluf(a01.y); t1[n0][c8+6]=siluf(a01.z); t1[n0][c8+7]=siluf(a01.w);
  t1[n1][c8+0]=siluf(a10.x); t1[n1][c8+1]=siluf(a10.y); t1[n1][c8+2]=siluf(a10.z); t1[n1][c8+3]=siluf(a10.w);
  t1[n1][c8+4]=siluf(a11.x); t1[n1][c8+5]=siluf(a11.y); t1[n1][c8+6]=siluf(a11.z); t1[n1][c8+7]=siluf(a11.w);
  __syncthreads();
  a00=*(const float4*)(b2+c8); a01=*(const float4*)(b2+c8+4);
  a10=a00; a11=a01;
  for(int kt=0;kt<8;kt++){
    { const float* src=w2+(size_t)(kt*16+ty)*128+c8;
      *(float4*)&wt[ty][c8]  =*(const float4*)src;
      *(float4*)&wt[ty][c8+4]=*(const float4*)(src+4); }
    __syncthreads();
    #pragma unroll
    for(int kk=0;kk<16;kk++){
      int k=kt*16+kk;
      float m0=t1[n0][k], m1=t1[n1][k];
      float4 wa=*(float4*)&wt[kk][c8], wb=*(float4*)&wt[kk][c8+4];
      a00.x+=m0*wa.x; a00.y+=m0*wa.y; a00.z+=m0*wa.z; a00.w+=m0*wa.w;
      a01.x+=m0*wb.x; a01.y+=m0*wb.y; a01.z+=m0*wb.z; a01.w+=m0*wb.w;
      a10.x+=m1*wa.x; a10.y+=m1*wa.y; a10.z+=m1*wa.z; a10.w+=m1*wa.w;
      a11.x+=m1*wb.x; a11.y+=m1*wb.y; a11.z+=m1*wb.z; a11.w+=m1*wb.w;
    }
    __syncthreads();
  }
  int gn0=g0+n0, gn1=g0+n1;
  if(gn0<NN){ *(float4*)(h+(size_t)gn0*128+c8)=a00; *(float4*)(h+(size_t)gn0*128+c8+4)=a01; }
  if(gn1<NN){ *(float4*)(h+(size_t)gn1*128+c8)=a10; *(float4*)(h+(size_t)gn1*128+c8+4)=a11; }
}

// B-fragment loads from bf16 LDS, generic stride (shorts); kbase dword-aligned
__device__ __forceinline__ short8 ldB(const unsigned short* base, int row, int kbase){
  const unsigned short* tp = base + row*TSTR + kbase;
  union { unsigned int u[4]; short8 s; } r;
  r.u[0] = *(const unsigned int*)(tp);
  r.u[1] = *(const unsigned int*)(tp+2);
  r.u[2] = *(const unsigned int*)(tp+4);
  r.u[3] = *(const unsigned int*)(tp+6);
  return r.s;
}
__device__ __forceinline__ short8 ldBs(const unsigned short* base, int row, int kbase, int stride){
  const unsigned short* tp = base + row*stride + kbase;
  union { unsigned int u[4]; short8 s; } r;
  r.u[0] = *(const unsigned int*)(tp);
  r.u[1] = *(const unsigned int*)(tp+2);
  r.u[2] = *(const unsigned int*)(tp+4);
  r.u[3] = *(const unsigned int*)(tp+6);
  return r.s;
}

// ==== MFMA k_pre: pa|pb = h @ [W1_pa|W1_pb] (+b1 on pa) ====
__global__ void __launch_bounds__(256)
k_preM(const float* __restrict__ h, const float* __restrict__ b1,
       const unsigned short* __restrict__ blob,
       float* __restrict__ pa, float* __restrict__ pb){
  __shared__ unsigned short cHi[32*130], cLo[32*130];
  int tid=threadIdx.x;
  int g0=blockIdx.x*32;
  { int n=tid>>3, c0=(tid&7)*16;
    int gn=g0+n; if(gn>=NN) gn=NN-1;
    const float* src=h+(size_t)gn*128+c0;
    #pragma unroll
    for(int q=0;q<4;q++){
      float4 v=*(const float4*)(src+q*4);
      unsigned h01,h23,l01,l23;
      split4(v.x,v.y,v.z,v.w,h01,h23,l01,l23);
      int o=n*130+c0+q*4;
      *(unsigned*)&cHi[o]=h01; *(unsigned*)&cHi[o+2]=h23;
      *(unsigned*)&cLo[o]=l01; *(unsigned*)&cLo[o+2]=l23;
    } }
  __syncthreads();
  int wl=tid>>6, lane=tid&63, q4=lane>>4, l15=lane&15;
  const short8* fr = (const short8*)blob;
  #pragma unroll
  for(int mi=0;mi<2;mi++){
    int mt = wl + mi*4;
    short8 A[4][2];
    #pragma unroll
    for(int kt=0;kt<4;kt++){
      A[kt][0]=fr[(size_t)((mt*4+kt)*2+0)*64+lane];
      A[kt][1]=fr[(size_t)((mt*4+kt)*2+1)*64+lane];
    }
    f32x4 acc0={0.f,0.f,0.f,0.f}, acc1=acc0;
    #pragma unroll
    for(int kt=0;kt<4;kt++){
      short8 bh0=ldBs(cHi, l15,    kt*32+q4*8, 130);
      short8 bl0=ldBs(cLo, l15,    kt*32+q4*8, 130);
      short8 bh1=ldBs(cHi, 16+l15, kt*32+q4*8, 130);
      short8 bl1=ldBs(cLo, 16+l15, kt*32+q4*8, 130);
      acc0=MFMA_BF16(A[kt][0],bh0,acc0); acc0=MFMA_BF16(A[kt][0],bl0,acc0); acc0=MFMA_BF16(A[kt][1],bh0,acc0);
      acc1=MFMA_BF16(A[kt][0],bh1,acc1); acc1=MFMA_BF16(A[kt][0],bl1,acc1); acc1=MFMA_BF16(A[kt][1],bh1,acc1);
    }
    int m0=mt*16+q4*4;
    float4 bias = (mt<4) ? *(const float4*)(b1+m0) : make_float4(0,0,0,0);
    #pragma unroll
    for(int nt=0;nt<2;nt++){
      f32x4 c = nt ? acc1 : acc0;
      int node=g0+nt*16+l15;
      if(node<NN){
        float4 o = make_float4(c[0]+bias.x, c[1]+bias.y, c[2]+bias.z, c[3]+bias.w);
        if (mt<4) *(float4*)(pa+(size_t)node*64+m0)=o;
        else      *(float4*)(pb+(size_t)node*64+(m0-64))=o;
      }
    }
  }
}

// ==== fused edge kernel — 3 GEMMs on MFMA; weights read from L2 (no LDS staging) ====
__global__ void __launch_bounds__(512,4)
k_edge2(const int2* __restrict__ sd, const unsigned short* __restrict__ efb,
        const float* __restrict__ x,
        const float* __restrict__ pa, const float* __restrict__ pb,
        const int* __restrict__ roff_dst,
        const float* __restrict__ w1,
        const float* __restrict__ b2,
        const float* __restrict__ xb1,
        const float* __restrict__ xw2, const float* __restrict__ xb2,
        const unsigned short* __restrict__ wblob,
        float* __restrict__ agg, float4* __restrict__ cvec){
  __shared__ unsigned short tHi[128*TSTR];   // 16,896 B
  __shared__ unsigned short tLo[128*TSTR];   // 16,896 B
  __shared__ float sqb[128], dxb[128], dyb[128], dzb[128];
  __shared__ int   sbuf[128], dbuf[128];
  int bid = blockIdx.x;
  int nb = (bid&7)*((int)gridDim.x>>3) + (bid>>3);
  int p0 = nb*EB;
  if (p0 >= NE) return;
  int tid = threadIdx.x;
  int wl = tid>>6, lane = tid&63;
  int q4 = lane>>4, l15 = lane&15;

  // B-frags for GEMM0 from pre-split efb (coalesced; zero for k>=16 lanes)
  int tile = nb*8 + wl;
  short8 ebh = {0,0,0,0,0,0,0,0};
  short8 ebl = ebh;
  if (lane < 32){
    const short8* ep = (const short8*)efb + (size_t)tile*64;
    ebh = ep[lane]; ebl = ep[lane+32];
  }

  if (tid < 128){
    int p = p0 + tid;
    int2 sdp = (p<NE) ? sd[p] : make_int2(0,0);
    float dx=0.f, dy=0.f, dz=0.f;
    if (p<NE){
      dx = x[sdp.x*3+0]-x[sdp.y*3+0];
      dy = x[sdp.x*3+1]-x[sdp.y*3+1];
      dz = x[sdp.x*3+2]-x[sdp.y*3+2];
    }
    sbuf[tid]=sdp.x; dbuf[tid]=sdp.y;
    sqb[tid]=dx*dx+dy*dy+dz*dz;
    dxb[tid]=dx; dyb[tid]=dy; dzb[tid]=dz;
  }
  __syncthreads();

  int rowb = 16*wl + l15;
  int s = sbuf[rowb], d = dbuf[rowb];
  float sqv = sqb[rowb];
  const short8* wfr = (const short8*)wblob;   // L2-resident; identical across blocks

  // ---- GEMM0 + exact fp32 epilogue, silu, trunc-split -> LDS ----
  #pragma unroll
  for(int mt=0;mt<4;mt++){
    short8 ah = wfr[(2*mt+0)*64+lane];
    short8 al = wfr[(2*mt+1)*64+lane];
    f32x4 c = {0.f,0.f,0.f,0.f};
    c = MFMA_BF16(ah, ebh, c);
    c = MFMA_BF16(ah, ebl, c);
    c = MFMA_BF16(al, ebh, c);
    float4 Ai = *(const float4*)(pa + (size_t)s*64 + mt*16 + q4*4);
    float4 Bi = *(const float4*)(pb + (size_t)d*64 + mt*16 + q4*4);
    float4 Wq = *(const float4*)(w1 + 256*64 + mt*16 + q4*4);
    float v0 = siluf(c[0] + Ai.x + Bi.x + sqv*Wq.x);
    float v1 = siluf(c[1] + Ai.y + Bi.y + sqv*Wq.y);
    float v2 = siluf(c[2] + Ai.z + Bi.z + sqv*Wq.z);
    float v3 = siluf(c[3] + Ai.w + Bi.w + sqv*Wq.w);
    unsigned h01,h23,l01,l23;
    split4(v0,v1,v2,v3,h01,h23,l01,l23);
    int mo = rowb*TSTR + mt*16 + q4*4;
    *(unsigned*)&tHi[mo]   = h01;
    *(unsigned*)&tHi[mo+2] = h23;
    *(unsigned*)&tLo[mo]   = l01;
    *(unsigned*)&tLo[mo+2] = l23;
  }
  // no barrier: wave reads only its own rows

  // ---- GEMM1: msg = silu(w2^T @ t + b2), repack trunc-split in place ----
  { short8 bh0 = ldB(tHi, rowb, q4*8);
    short8 bh1 = ldB(tHi, rowb, 32 + q4*8);
    short8 bl0 = ldB(tLo, rowb, q4*8);
    short8 bl1 = ldB(tLo, rowb, 32 + q4*8);
    #pragma unroll
    for(int mt=0;mt<4;mt++){
      short8 ah0 = wfr[(8+mt*4+0)*64+lane];
      short8 al0 = wfr[(8+mt*4+1)*64+lane];
      short8 ah1 = wfr[(8+mt*4+2)*64+lane];
      short8 al1 = wfr[(8+mt*4+3)*64+lane];
      f32x4 c = {0.f,0.f,0.f,0.f};
      c = MFMA_BF16(ah0,bh0,c); c = MFMA_BF16(ah0,bl0,c); c = MFMA_BF16(al0,bh0,c);
      c = MFMA_BF16(ah1,bh1,c); c = MFMA_BF16(ah1,bl1,c); c = MFMA_BF16(al1,bh1,c);
      float4 bb = *(const float4*)(b2 + mt*16 + q4*4);
      float v0=siluf(c[0]+bb.x), v1=siluf(c[1]+bb.y), v2=siluf(c[2]+bb.z), v3=siluf(c[3]+bb.w);
      unsigned h01,h23,l01,l23;
      split4(v0,v1,v2,v3,h01,h23,l01,l23);
      int mo = rowb*TSTR + mt*16 + q4*4;
      *(unsigned*)&tHi[mo]   = h01;
      *(unsigned*)&tHi[mo+2] = h23;
      *(unsigned*)&tLo[mo]   = l01;
      *(unsigned*)&tLo[mo+2] = l23;
    } }

  // ---- GEMM2: xh = xw1^T @ msg; w = silu(xh)·xw2 + xb2; stream cvec ----
  { short8 mh0 = ldB(tHi, rowb, q4*8);
    short8 mh1 = ldB(tHi, rowb, 32 + q4*8);
    short8 ml0 = ldB(tLo, rowb, q4*8);
    short8 ml1 = ldB(tLo, rowb, 32 + q4*8);
    float part = 0.f;
    #pragma unroll
    for(int mt=0;mt<4;mt++){
      short8 ah0 = wfr[(24+mt*4+0)*64+lane];
      short8 al0 = wfr[(24+mt*4+1)*64+lane];
      short8 ah1 = wfr[(24+mt*4+2)*64+lane];
      short8 al1 = wfr[(24+mt*4+3)*64+lane];
      f32x4 c = {0.f,0.f,0.f,0.f};
      c = MFMA_BF16(ah0,mh0,c); c = MFMA_BF16(ah0,ml0,c); c = MFMA_BF16(al0,mh0,c);
      c = MFMA_BF16(ah1,mh1,c); c = MFMA_BF16(ah1,ml1,c); c = MFMA_BF16(al1,mh1,c);
      float4 xb  = *(const float4*)(xb1 + mt*16 + q4*4);
      float4 wv4 = *(const float4*)(xw2 + mt*16 + q4*4);
      part += siluf(c[0]+xb.x)*wv4.x + siluf(c[1]+xb.y)*wv4.y
            + siluf(c[2]+xb.z)*wv4.z + siluf(c[3]+xb.w)*wv4.w;
    }
    part += __shfl_xor(part,16);
    part += __shfl_xor(part,32);
    int pw = p0 + rowb;
    if (q4==0 && pw < NE){
      float wv = part + xb2[0];
      cvec[pw] = make_float4(dxb[rowb]*wv, dyb[rowb]*wv, dzb[rowb]*wv, 0.f);
    }
  }
  __syncthreads();                 // msg final (all rows)

  // ---- fused segmented reduction over dst: 2 cols/thread, dword reads ----
  int pend = (p0+EB < NE) ? (p0+EB) : NE;
  int dfirst = sd[p0].y;
  int dlast  = sd[pend-1].y;
  int jj = (tid&31)*2, slot = tid>>5;
  for (int n=dfirst+slot; n<=dlast; n+=16){
    int rs0 = roff_dst[n], re0 = roff_dst[n+1];
    int rs = (rs0 > p0)   ? rs0 : p0;
    int re = (re0 < pend) ? re0 : pend;
    rs -= p0; re -= p0;
    if (re > rs){
      float s0=0.f, s1=0.f;
      for (int r=rs; r<re; r++){
        unsigned dh = *(const unsigned*)&tHi[r*TSTR+jj];
        unsigned dl = *(const unsigned*)&tLo[r*TSTR+jj];
        s0 += __uint_as_float(dh<<16) + __uint_as_float(dl<<16);
        s1 += __uint_as_float(dh&0xFFFF0000u) + __uint_as_float(dl&0xFFFF0000u);
      }
      if (rs0 >= p0 && re0 <= pend){
        float2 o = make_float2(s0,s1);
        *(float2*)&agg[(size_t)n*64+jj] = o;
      } else {
        atomicAdd(&agg[(size_t)n*64+jj], s0);
        atomicAdd(&agg[(size_t)n*64+jj+1], s1);
      }
    }
  }
}

// ---- phase C: 16 lanes per src node; pure sum of precomputed cvec ----
__global__ void k_coordC(const int* __restrict__ roff_src, const int* __restrict__ slist,
                         const float4* __restrict__ cvec, float* __restrict__ cacc){
  int tid=threadIdx.x;
  int grp=tid>>4, sub=tid&15;
  int n = blockIdx.x*16 + grp;
  if (n >= NN) return;
  int s = roff_src[n], e2 = roff_src[n+1];
  float a0=0.f, a1=0.f, a2=0.f;
  for (int p=s+sub; p<e2; p+=16){
    float4 c = cvec[slist[p]];
    a0 += c.x; a1 += c.y; a2 += c.z;
  }
  #pragma unroll
  for(int off=1; off<16; off<<=1){
    a0 += __shfl_xor(a0, off);
    a1 += __shfl_xor(a1, off);
    a2 += __shfl_xor(a2, off);
  }
  if (sub==0){
    cacc[n*3+0]=a0; cacc[n*3+1]=a1; cacc[n*3+2]=a2;
  }
}

// ==== MFMA k_node (trunc-split prologue/epilogue) ====
__global__ void __launch_bounds__(256)
k_nodeM(const float* __restrict__ agg, const float* __restrict__ cacc,
        const float* __restrict__ cntinv,
        const float* __restrict__ hb1, const float* __restrict__ hb2,
        const float* __restrict__ lng, const float* __restrict__ lnb,
        const unsigned short* __restrict__ nbase,
        float* __restrict__ h, float* __restrict__ x){
  __shared__ float hsf[32][132];
  __shared__ unsigned short cHi[32*194], cLo[32*194];
  __shared__ unsigned short t2Hi[32*130], t2Lo[32*130];
  __shared__ float psA[32][8], psB[32][8];
  __shared__ float mu_s[32], rs_s[32];
  int tid=threadIdx.x;
  int g0=blockIdx.x*32;
  { int n=tid>>3, c0=(tid&7)*16;
    int gn=g0+n; if(gn>=NN) gn=NN-1;
    const float* src=h+(size_t)gn*128+c0;
    #pragma unroll
    for(int q=0;q<4;q++){
      float4 v=*(const float4*)(src+q*4);
      *(float4*)&hsf[n][c0+q*4]=v;
      unsigned h01,h23,l01,l23;
      split4(v.x,v.y,v.z,v.w,h01,h23,l01,l23);
      int o=n*194+c0+q*4;
      *(unsigned*)&cHi[o]=h01; *(unsigned*)&cHi[o+2]=h23;
      *(unsigned*)&cLo[o]=l01; *(unsigned*)&cLo[o+2]=l23;
    }
    float ci=cntinv[gn];
    int ca=(tid&7)*8;
    const float* srca=agg+(size_t)gn*64+ca;
    #pragma unroll
    for(int q=0;q<2;q++){
      float4 v=*(const float4*)(srca+q*4);
      unsigned h01,h23,l01,l23;
      split4(v.x*ci,v.y*ci,v.z*ci,v.w*ci,h01,h23,l01,l23);
      int o=n*194+128+ca+q*4;
      *(unsigned*)&cHi[o]=h01; *(unsigned*)&cHi[o+2]=h23;
      *(unsigned*)&cLo[o]=l01; *(unsigned*)&cLo[o+2]=l23;
    } }
  __syncthreads();
  int wl=tid>>6, lane=tid&63, q4=lane>>4, l15=lane&15;
  const short8* f1 = (const short8*)(nbase + 32768);
  const short8* f2 = (const short8*)(nbase + 81920);
  // GEMM1: t = silu(cat @ hw1 + hb1), K=192
  #pragma unroll
  for(int mi=0;mi<2;mi++){
    int mt=wl+mi*4;
    short8 A[6][2];
    #pragma unroll
    for(int kt=0;kt<6;kt++){
      A[kt][0]=f1[(size_t)((mt*6+kt)*2+0)*64+lane];
      A[kt][1]=f1[(size_t)((mt*6+kt)*2+1)*64+lane];
    }
    f32x4 acc0={0.f,0.f,0.f,0.f}, acc1=acc0;
    #pragma unroll
    for(int kt=0;kt<6;kt++){
      short8 bh0=ldBs(cHi, l15,    kt*32+q4*8, 194);
      short8 bl0=ldBs(cLo, l15,    kt*32+q4*8, 194);
      short8 bh1=ldBs(cHi, 16+l15, kt*32+q4*8, 194);
      short8 bl1=ldBs(cLo, 16+l15, kt*32+q4*8, 194);
      acc0=MFMA_BF16(A[kt][0],bh0,acc0); acc0=MFMA_BF16(A[kt][0],bl0,acc0); acc0=MFMA_BF16(A[kt][1],bh0,acc0);
      acc1=MFMA_BF16(A[kt][0],bh1,acc1); acc1=MFMA_BF16(A[kt][0],bl1,acc1); acc1=MFMA_BF16(A[kt][1],bh1,acc1);
    }
    int m0=mt*16+q4*4;
    float4 bias=*(const float4*)(hb1+m0);
    #pragma unroll
    for(int nt=0;nt<2;nt++){
      f32x4 c = nt ? acc1 : acc0;
      int row=nt*16+l15;
      float v0=siluf(c[0]+bias.x), v1=siluf(c[1]+bias.y), v2=siluf(c[2]+bias.z), v3=siluf(c[3]+bias.w);
      unsigned h01,h23,l01,l23;
      split4(v0,v1,v2,v3,h01,h23,l01,l23);
      int mo=row*130+m0;
      *(unsigned*)&t2Hi[mo]=h01; *(unsigned*)&t2Hi[mo+2]=h23;
      *(unsigned*)&t2Lo[mo]=l01; *(unsigned*)&t2Lo[mo+2]=l23;
    }
  }
  __syncthreads();
  // GEMM2: dh = t @ hw2 + hb2; hsf += dh
  #pragma unroll
  for(int mi=0;mi<2;mi++){
    int mt=wl+mi*4;
    short8 A[4][2];
    #pragma unroll
    for(int kt=0;kt<4;kt++){
      A[kt][0]=f2[(size_t)((mt*4+kt)*2+0)*64+lane];
      A[kt][1]=f2[(size_t)((mt*4+kt)*2+1)*64+lane];
    }
    f32x4 acc0={0.f,0.f,0.f,0.f}, acc1=acc0;
    #pragma unroll
    for(int kt=0;kt<4;kt++){
      short8 bh0=ldBs(t2Hi, l15,    kt*32+q4*8, 130);
      short8 bl0=ldBs(t2Lo, l15,    kt*32+q4*8, 130);
      short8 bh1=ldBs(t2Hi, 16+l15, kt*32+q4*8, 130);
      short8 bl1=ldBs(t2Lo, 16+l15, kt*32+q4*8, 130);
      acc0=MFMA_BF16(A[kt][0],bh0,acc0); acc0=MFMA_BF16(A[kt][0],bl0,acc0); acc0=MFMA_BF16(A[kt][1],bh0,acc0);
      acc1=MFMA_BF16(A[kt][0],bh1,acc1); acc1=MFMA_BF16(A[kt][0],bl1,acc1); acc1=MFMA_BF16(A[kt][1],bh1,acc1);
    }
    int m0=mt*16+q4*4;
    float4 bias=*(const float4*)(hb2+m0);
    #pragma unroll
    for(int nt=0;nt<2;nt++){
      f32x4 c = nt ? acc1 : acc0;
      int row=nt*16+l15;
      hsf[row][m0+0]+=c[0]+bias.x;
      hsf[row][m0+1]+=c[1]+bias.y;
      hsf[row][m0+2]+=c[2]+bias.z;
      hsf[row][m0+3]+=c[3]+bias.w;
    }
  }
  __syncthreads();
  // LayerNorm (fp32, exact)
  { int rid=tid>>3, sub=tid&7;
    float sm=0.f, ss=0.f;
    #pragma unroll
    for(int i=0;i<16;i++){ float v=hsf[rid][sub*16+i]; sm+=v; ss+=v*v; }
    psA[rid][sub]=sm; psB[rid][sub]=ss; }
  __syncthreads();
  { int rid=tid>>3, sub=tid&7;
    if(sub==0){
      float sm=0.f, ss=0.f;
      #pragma unroll
      for(int i=0;i<8;i++){ sm+=psA[rid][i]; ss+=psB[rid][i]; }
      float mu=sm*(1.0f/128.0f);
      float var=ss*(1.0f/128.0f)-mu*mu;
      mu_s[rid]=mu; rs_s[rid]=rsqrtf(fmaxf(var,0.0f)+1e-5f);
    } }
  __syncthreads();
  { int rid=tid>>3, sub=tid&7;
    int gn=g0+rid;
    if(gn<NN){
      float mu=mu_s[rid], rs=rs_s[rid];
      int c0=sub*16;
      #pragma unroll
      for(int q=0;q<4;q++){
        float4 g4=*(const float4*)(lng+c0+q*4);
        float4 b4=*(const float4*)(lnb+c0+q*4);
        float4 o;
        o.x=(hsf[rid][c0+q*4+0]-mu)*rs*g4.x+b4.x;
        o.y=(hsf[rid][c0+q*4+1]-mu)*rs*g4.y+b4.y;
        o.z=(hsf[rid][c0+q*4+2]-mu)*rs*g4.z+b4.z;
        o.w=(hsf[rid][c0+q*4+3]-mu)*rs*g4.w+b4.w;
        *(float4*)(h+(size_t)gn*128+c0+q*4)=o;
      }
    } }
  if(tid<32){
    int gn=g0+tid;
    if(gn<NN){
      float ci=cntinv[gn];
      x[gn*3+0]+=cacc[gn*3+0]*ci;
      x[gn*3+1]+=cacc[gn*3+1]*ci;
      x[gn*3+2]+=cacc[gn*3+2]*ci;
    }
  }
}

// ---- readout (unchanged) ----
__device__ __forceinline__ int lowerb(const int* a, int n, int v){
  int lo=0, hi=n;
  while(lo<hi){ int mid=(lo+hi)>>1; if(a[mid]<v) lo=mid+1; else hi=mid; }
  return lo;
}

__global__ void k_readout(const int* __restrict__ batch, const float* __restrict__ h,
                          const float* __restrict__ w1, const float* __restrict__ b1,
                          const float* __restrict__ w2, const float* __restrict__ b2,
                          const float* __restrict__ w3, const float* __restrict__ b3,
                          float* __restrict__ out){
  int g = blockIdx.x;
  int wl = threadIdx.x>>6, lane = threadIdx.x&63;
  __shared__ float part[4][128];
  __shared__ float gh[128];
  __shared__ float r1[128];
  __shared__ float r2[64];
  int start = lowerb(batch, NN, g);
  int end   = lowerb(batch, NN, g+1);
  float s0=0.f, s1=0.f;
  for(int n=start+wl; n<end; n+=4){
    s0 += h[(size_t)n*128+2*lane];
    s1 += h[(size_t)n*128+2*lane+1];
  }
  part[wl][2*lane]=s0; part[wl][2*lane+1]=s1;
  __syncthreads();
  float ci = 1.0f/fmaxf((float)(end-start),1.0f);
  if(wl==0){
    gh[2*lane]   = (part[0][2*lane]+part[1][2*lane]+part[2][2*lane]+part[3][2*lane])*ci;
    gh[2*lane+1] = (part[0][2*lane+1]+part[1][2*lane+1]+part[2][2*lane+1]+part[3][2*lane+1])*ci;
  }
  __syncthreads();
  if(wl==0){
    float a0=b1[2*lane], a1=b1[2*lane+1];
    for(int k=0;k<128;k++){
      float m=gh[k];
      float2 w=((const float2*)(w1+k*128))[lane];
      a0+=m*w.x; a1+=m*w.y;
    }
    r1[2*lane]=siluf(a0); r1[2*lane+1]=siluf(a1);
  }
  __syncthreads();
  if(wl==0){
    float b=b2[lane];
    for(int k=0;k<128;k++) b += r1[k]*w2[k*64+lane];
    r2[lane]=siluf(b);
  }
  __syncthreads();
  if(wl==0 && lane<2){
    float o=b3[lane];
    for(int k=0;k<64;k++) o += r2[k]*w3[k*2+lane];
    out[g*2+lane]=o;
  }
}

extern "C" void kernel_launch(void* const* d_in, const int* in_sizes, int n_in,
                              void* d_out, int out_size, void* d_ws, size_t ws_size,
                              hipStream_t stream){
  const float* nf     = (const float*)d_in[0];
  const float* coords = (const float*)d_in[1];
  const int*   ei     = (const int*)d_in[2];
  const float* ef     = (const float*)d_in[3];
  const int*   batch  = (const int*)d_in[4];

  const float* enc_w1 = (const float*)d_in[5];
  const float* enc_b1 = (const float*)d_in[6];
  const float* enc_w2 = (const float*)d_in[7];
  const float* enc_b2 = (const float*)d_in[8];
  const float* pe_w1  = (const float*)d_in[9];
  const float* pe_b1  = (const float*)d_in[10];
  const float* pe_w2  = (const float*)d_in[11];
  const float* pe_b2  = (const float*)d_in[12];
  const float* ph_w1  = (const float*)d_in[13];
  const float* ph_b1  = (const float*)d_in[14];
  const float* ph_w2  = (const float*)d_in[15];
  const float* ph_b2  = (const float*)d_in[16];
  const float* px_w1  = (const float*)d_in[17];
  const float* px_b1  = (const float*)d_in[18];
  const float* px_w2  = (const float*)d_in[19];
  const float* px_b2  = (const float*)d_in[20];
  const float* ln_g   = (const float*)d_in[21];
  const float* ln_b   = (const float*)d_in[22];
  const float* ro_w1  = (const float*)d_in[23];
  const float* ro_b1  = (const float*)d_in[24];
  const float* ro_w2  = (const float*)d_in[25];
  const float* ro_b2  = (const float*)d_in[26];
  const float* ro_w3  = (const float*)d_in[27];
  const float* ro_b3  = (const float*)d_in[28];

  char* wsb = (char*)d_ws;
  size_t off = 0;
  auto alloc_f = [&](size_t nfl)->float*{ float* p=(float*)(wsb+off); off+=nfl*4; return p; };
  auto alloc_i = [&](size_t nin)->int*  { int*   p=(int*)(wsb+off);   off+=nin*4; return p; };

  float* h      = alloc_f((size_t)NN*128);
  float* x      = alloc_f((size_t)NN*3);
  float* agg    = alloc_f((size_t)NN*64);
  float* cacc   = alloc_f((size_t)NN*3);
  float* cntinv = alloc_f(NN);
  float* pa     = alloc_f((size_t)NN*64);
  float* pb     = alloc_f((size_t)NN*64);
  float4* cvec  = (float4*)alloc_f((size_t)NE*4);        // 16 MB streaming per layer
  unsigned short* efb = (unsigned short*)alloc_f((size_t)NE*16 + 2048); // 64 MB + tail pad
  int2*  sd_s   = (int2*)alloc_i((size_t)NE*2);
  unsigned short* wblob = (unsigned short*)alloc_i((size_t)NL*40*512/2);   // 245,760 B
  unsigned short* nblob = (unsigned short*)alloc_i((size_t)NL*224*512/2);  // 1,376,256 B
  int* roff_dst = alloc_i(NN+1);
  int* roff_src = alloc_i(NN+1);
  int* dlist    = alloc_i(NE);
  int* slist    = alloc_i(NE);
  int* bsum     = alloc_i(256);
  int* bbase    = alloc_i(256);
  int* cnt_dst  = alloc_i(NN);   // cnt_dst..cur_src contiguous -> one memset
  int* cnt_src  = alloc_i(NN);
  int* cur_dst  = alloc_i(NN);
  int* cur_src  = alloc_i(NN);

  hipMemsetAsync(cnt_dst, 0, (size_t)4*NN*sizeof(int), stream);
  k_degrees<<<(NE+255)/256,256,0,stream>>>(ei, cnt_dst, cnt_src);
  k_scan1<<<NB_SCAN,256,0,stream>>>(cnt_dst, roff_dst, bsum);
  k_scan2<<<1,256,0,stream>>>(bsum, bbase, roff_dst);
  k_scan3<<<NB_SCAN,256,0,stream>>>(roff_dst, bbase);
  k_scan1<<<NB_SCAN,256,0,stream>>>(cnt_src, roff_src, bsum);
  k_scan2<<<1,256,0,stream>>>(bsum, bbase, roff_src);
  k_scan3<<<NB_SCAN,256,0,stream>>>(roff_src, bbase);
  k_fill<<<(NE+255)/256,256,0,stream>>>(ei, roff_dst, roff_src, cur_dst, cur_src, dlist, slist);
  k_gather<<<(NE+255)/256,256,0,stream>>>(ei, ef, dlist, sd_s, efb);
  k_prep<<<(NN+255)/256,256,0,stream>>>(coords, cnt_dst, x, cntinv);
  k_wprep<<<(NL*40*64+255)/256,256,0,stream>>>(pe_w1, pe_w2, px_w1, wblob);
  k_wprep2<<<(NL*224*64+255)/256,256,0,stream>>>(pe_w1, ph_w1, ph_w2, nblob);
  k_encoder<<<(NN+31)/32,256,0,stream>>>(nf, enc_w1, enc_b1, enc_w2, enc_b2, h);

  int G  = (NE+EB-1)/EB;
  int G8 = ((G+7)/8)*8;

  for(int l=0;l<NL;l++){
    const unsigned short* nbl = nblob + (size_t)l*224*512;
    k_preM<<<(NN+31)/32,256,0,stream>>>(h, pe_b1+l*64, nbl, pa, pb);
    hipMemsetAsync(agg, 0, (size_t)NN*64*sizeof(float), stream);
    k_edge2<<<G8,512,0,stream>>>(sd_s, efb, x, pa, pb, roff_dst,
        pe_w1+(size_t)l*273*64,
        pe_b2+l*64,
        px_b1+l*64,
        px_w2+l*64, px_b2+l,
        wblob + (size_t)l*40*512,
        agg, cvec);
    k_coordC<<<(NN+15)/16,256,0,stream>>>(roff_src, slist, cvec, cacc);
    k_nodeM<<<(NN+31)/32,256,0,stream>>>(agg, cacc, cntinv,
        ph_b1+l*128, ph_b2+l*128,
        ln_g+l*128, ln_b+l*128, nbl, h, x);
  }

  k_readout<<<NG,256,0,stream>>>(batch, h,
      ro_w1, ro_b1, ro_w2, ro_b2, ro_w3, ro_b3, (float*)d_out);
}

// Round 7
// 1801.907 us; speedup vs baseline: 1.1339x; 1.1339x over previous
//
#include <hip/hip_runtime.h>
#include <hip/hip_bf16.h>

#define NN 50000
#define NE 1000000
#define NG 256
#define NL 6
#define NB_SCAN 196   // ceil(NN/256)
#define EB 128        // edges per block in k_edge2
#define TSTR 66       // bf16 stride per LDS row in k_edge2 (132 B; conflict-free)

typedef float v2f __attribute__((ext_vector_type(2)));
typedef short short8 __attribute__((ext_vector_type(8)));   // 8 bf16 (4 VGPRs) MFMA frag
typedef float f32x4 __attribute__((ext_vector_type(4)));    // MFMA accum

#define MFMA_BF16(a,b,c) __builtin_amdgcn_mfma_f32_16x16x32_bf16(a,b,c,0,0,0)

// silu via hardware rcp (v_rcp_f32, ~1e-7 rel err)
__device__ __forceinline__ float siluf(float v){
  return v * __builtin_amdgcn_rcpf(1.0f + __expf(-v));
}

// bf16 helpers (RNE — used for WEIGHT prep only; activations use trunc-split below)
__device__ __forceinline__ unsigned f2bf(float x){
  unsigned u = __float_as_uint(x);
  return (u + 0x7FFFu + ((u>>16)&1u)) >> 16;
}
__device__ __forceinline__ float bf2f(unsigned h){
  return __uint_as_float(h<<16);
}

// pack hi16(a) | hi16(b)<<16 in ONE v_perm_b32
__device__ __forceinline__ unsigned pkhi(unsigned a, unsigned b){
  return __builtin_amdgcn_perm(b, a, 0x07060302u);
}
// trunc-split 4 values into packed bf16 hi pairs + lo (trunc of exact residual) pairs.
__device__ __forceinline__ void split4(float v0,float v1,float v2,float v3,
                                       unsigned &h01, unsigned &h23,
                                       unsigned &l01, unsigned &l23){
  unsigned u0=__float_as_uint(v0),u1=__float_as_uint(v1);
  unsigned u2=__float_as_uint(v2),u3=__float_as_uint(v3);
  h01=pkhi(u0,u1); h23=pkhi(u2,u3);
  float r0=v0-__uint_as_float(u0&0xFFFF0000u);
  float r1=v1-__uint_as_float(u1&0xFFFF0000u);
  float r2=v2-__uint_as_float(u2&0xFFFF0000u);
  float r3=v3-__uint_as_float(u3&0xFFFF0000u);
  l01=pkhi(__float_as_uint(r0),__float_as_uint(r1));
  l23=pkhi(__float_as_uint(r2),__float_as_uint(r3));
}

// ---- degree counts (dst + src) ----
__global__ void k_degrees(const int* __restrict__ ei, int* __restrict__ cnt_dst,
                          int* __restrict__ cnt_src){
  int e = blockIdx.x*256 + threadIdx.x;
  if (e<NE){
    atomicAdd(&cnt_dst[ei[NE+e]], 1);
    atomicAdd(&cnt_src[ei[e]], 1);
  }
}

// ---- hierarchical scan ----
__global__ void k_scan1(const int* __restrict__ cnt, int* __restrict__ roff,
                        int* __restrict__ bsum){
  __shared__ int sd[256];
  int t=threadIdx.x; int i=blockIdx.x*256+t;
  int v=(i<NN)?cnt[i]:0;
  sd[t]=v; __syncthreads();
  #pragma unroll
  for(int off=1;off<256;off<<=1){
    int xv=(t>=off)?sd[t-off]:0; __syncthreads();
    sd[t]+=xv; __syncthreads();
  }
  if(i<NN) roff[i]=sd[t]-v;
  if(t==255) bsum[blockIdx.x]=sd[t];
}
__global__ void k_scan2(const int* __restrict__ bsum, int* __restrict__ bbase,
                        int* __restrict__ roff){
  __shared__ int sd[256];
  int t=threadIdx.x;
  int v=(t<NB_SCAN)?bsum[t]:0;
  sd[t]=v; __syncthreads();
  #pragma unroll
  for(int off=1;off<256;off<<=1){
    int xv=(t>=off)?sd[t-off]:0; __syncthreads();
    sd[t]+=xv; __syncthreads();
  }
  if(t<NB_SCAN) bbase[t]=sd[t]-v;
  if(t==255) roff[NN]=sd[t];
}
__global__ void k_scan3(int* __restrict__ roff, const int* __restrict__ bbase){
  int i=blockIdx.x*256+threadIdx.x;
  if(i<NN) roff[i]+=bbase[blockIdx.x];
}

// ---- scatter-fill: dlist = edge ids dst-sorted; slist = dst-sorted POSITIONS per src ----
__global__ void k_fill(const int* __restrict__ ei,
                       const int* __restrict__ roff_dst, const int* __restrict__ roff_src,
                       int* __restrict__ cur_dst, int* __restrict__ cur_src,
                       int* __restrict__ dlist, int* __restrict__ slist){
  int e = blockIdx.x*256 + threadIdx.x;
  if (e<NE){
    int d = ei[NE+e];
    int pd = roff_dst[d] + atomicAdd(&cur_dst[d],1);
    dlist[pd] = e;
    int s = ei[e];
    int ps = roff_src[s] + atomicAdd(&cur_src[s],1);
    slist[ps] = pd;
  }
}

// ---- one-time gather into dst-sorted order + ef -> B-fragment bf16 hi/lo tiles ----
__global__ void k_gather(const int* __restrict__ ei, const float* __restrict__ ef,
                         const int* __restrict__ dlist,
                         int2* __restrict__ sd_s, unsigned short* __restrict__ efb){
  int p = blockIdx.x*256 + threadIdx.x;
  if (p<NE){
    int e = dlist[p];
    sd_s[p] = make_int2(ei[e], ei[NE+e]);
    int tile = p>>4, l15 = p&15;
    size_t hb = (size_t)tile*512 + (size_t)l15*8;
    const float4* src = (const float4*)(ef + (size_t)e*16);
    #pragma unroll
    for(int q=0;q<4;q++){
      float4 v = src[q];
      float vv[4] = {v.x, v.y, v.z, v.w};
      #pragma unroll
      for(int r=0;r<4;r++){
        int k = q*4+r;
        unsigned h  = f2bf(vv[r]);
        unsigned lo = f2bf(vv[r]-bf2f(h));
        size_t o = hb + (size_t)(k>>3)*128 + (k&7);
        efb[o]     = (unsigned short)h;
        efb[o+256] = (unsigned short)lo;
      }
    }
  }
}

// ---- init coords + 1/max(indeg,1) ----
__global__ void k_prep(const float* __restrict__ coords,
                       const int* __restrict__ cnt,
                       float* __restrict__ x, float* __restrict__ cntinv){
  int n = blockIdx.x*256+threadIdx.x;
  if (n<NN){
    x[n*3+0]=coords[n*3+0];
    x[n*3+1]=coords[n*3+1];
    x[n*3+2]=coords[n*3+2];
    cntinv[n]=1.0f/fmaxf((float)cnt[n],1.0f);
  }
}

// ---- one-time weight prep: edge-kernel blobs (RNE hi/lo) ----
__global__ void k_wprep(const float* __restrict__ w1full, const float* __restrict__ w2,
                        const float* __restrict__ xw1,
                        unsigned short* __restrict__ blob){
  int t = blockIdx.x*256 + threadIdx.x;
  if (t >= NL*40*64) return;
  int lane = t & 63;
  int f = (t>>6) % 40;
  int l = t / (40*64);
  int m, hl;
  unsigned short* out = blob + (size_t)t*8;
  if (f < 8){
    int mt = f>>1; hl = f&1;
    m = mt*16 + (lane&15);
    int kb = (lane>>4)*8;
    #pragma unroll
    for(int j=0;j<8;j++){
      int k = kb + j;
      float v = (k<16) ? w1full[(size_t)l*273*64 + (size_t)(257+k)*64 + m] : 0.f;
      unsigned h = f2bf(v);
      if (hl) h = f2bf(v - bf2f(h));
      out[j] = (unsigned short)h;
    }
  } else {
    int fi = (f<24) ? (f-8) : (f-24);
    const float* W = ((f<24) ? w2 : xw1) + (size_t)l*4096;
    int mt = fi>>2, kt = (fi>>1)&1; hl = fi&1;
    m = mt*16 + (lane&15);
    int kb = kt*32 + (lane>>4)*8;
    #pragma unroll
    for(int j=0;j<8;j++){
      float v = W[(size_t)(kb+j)*64 + m];
      unsigned h = f2bf(v);
      if (hl) h = f2bf(v - bf2f(h));
      out[j] = (unsigned short)h;
    }
  }
}

// ---- one-time weight prep: node-side blobs (RNE hi/lo) ----
__global__ void k_wprep2(const float* __restrict__ pw1, const float* __restrict__ hw1,
                         const float* __restrict__ hw2, unsigned short* __restrict__ blob){
  int t = blockIdx.x*256 + threadIdx.x;
  if (t >= NL*224*64) return;
  int lane = t & 63;
  int f = (t>>6) % 224;
  int l = t / (224*64);
  int m15 = lane & 15, kq = (lane>>4)*8;
  unsigned short* out = blob + (size_t)t*8;
  if (f < 64){
    int mt = f>>3, kt = (f>>1)&3, hl = f&1;
    int m = mt*16 + m15;
    const float* W = pw1 + (size_t)l*273*64;
    #pragma unroll
    for(int j=0;j<8;j++){
      int k = kt*32 + kq + j;
      float v = (m<64) ? W[(size_t)k*64 + m] : W[(size_t)(128+k)*64 + (m-64)];
      unsigned hb = f2bf(v);
      if (hl) hb = f2bf(v - bf2f(hb));
      out[j] = (unsigned short)hb;
    }
  } else if (f < 160){
    int fi = f - 64;
    int mt = fi/12, r = fi%12, kt = r>>1, hl = r&1;
    int m = mt*16 + m15;
    const float* W = hw1 + (size_t)l*192*128;
    #pragma unroll
    for(int j=0;j<8;j++){
      int k = kt*32 + kq + j;
      float v = W[(size_t)k*128 + m];
      unsigned hb = f2bf(v);
      if (hl) hb = f2bf(v - bf2f(hb));
      out[j] = (unsigned short)hb;
    }
  } else {
    int fi = f - 160;
    int mt = fi>>3, kt = (fi>>1)&3, hl = fi&1;
    int m = mt*16 + m15;
    const float* W = hw2 + (size_t)l*128*128;
    #pragma unroll
    for(int j=0;j<8;j++){
      int k = kt*32 + kq + j;
      float v = W[(size_t)k*128 + m];
      unsigned hb = f2bf(v);
      if (hl) hb = f2bf(v - bf2f(hb));
      out[j] = (unsigned short)hb;
    }
  }
}

// ==== tiled encoder (unchanged) ====
__global__ void __launch_bounds__(256)
k_encoder(const float* __restrict__ nf,
          const float* __restrict__ w1, const float* __restrict__ b1,
          const float* __restrict__ w2, const float* __restrict__ b2,
          float* __restrict__ h){
  __shared__ float in1[32][17];
  __shared__ float t1[32][129];
  __shared__ float wt[16][136];
  int tid=threadIdx.x;
  int g0=blockIdx.x*32;
  int ty=tid>>4, tx=tid&15;
  int n0=ty*2, n1=ty*2+1;
  { int n=tid>>3, c=(tid&7)*2;
    int gn=g0+n; if(gn>=NN) gn=NN-1;
    float2 v=*(const float2*)(nf+(size_t)gn*16+c);
    in1[n][c]=v.x; in1[n][c+1]=v.y; }
  { int c=tx*8;
    const float* src=w1+(size_t)ty*128+c;
    *(float4*)&wt[ty][c]  =*(const float4*)src;
    *(float4*)&wt[ty][c+4]=*(const float4*)(src+4); }
  __syncthreads();
  float4 a00,a01,a10,a11;
  a00=*(const float4*)(b1+tx*8); a01=*(const float4*)(b1+tx*8+4);
  a10=a00; a11=a01;
  #pragma unroll
  for(int k=0;k<16;k++){
    float m0=in1[n0][k], m1=in1[n1][k];
    float4 wa=*(float4*)&wt[k][tx*8], wb=*(float4*)&wt[k][tx*8+4];
    a00.x+=m0*wa.x; a00.y+=m0*wa.y; a00.z+=m0*wa.z; a00.w+=m0*wa.w;
    a01.x+=m0*wb.x; a01.y+=m0*wb.y; a01.z+=m0*wb.z; a01.w+=m0*wb.w;
    a10.x+=m1*wa.x; a10.y+=m1*wa.y; a10.z+=m1*wa.z; a10.w+=m1*wa.w;
    a11.x+=m1*wb.x; a11.y+=m1*wb.y; a11.z+=m1*wb.z; a11.w+=m1*wb.w;
  }
  int c8=tx*8;
  t1[n0][c8+0]=siluf(a00.x); t1[n0][c8+1]=siluf(a00.y); t1[n0][c8+2]=siluf(a00.z); t1[n0][c8+3]=siluf(a00.w);
  t1[n0][c8+4]=siluf(a01.x); t1[n0][c8+5]=siluf(a01.y); t1[n0][c8+6]=siluf(a01.z); t1[n0][c8+7]=siluf(a01.w);
  t1[n1][c8+0]=siluf(a10.x); t1[n1][c8+1]=siluf(a10.y); t1[n1][c8+2]=siluf(a10.z); t1[n1][c8+3]=siluf(a10.w);
  t1[n1][c8+4]=siluf(a11.x); t1[n1][c8+5]=siluf(a11.y); t1[n1][c8+6]=siluf(a11.z); t1[n1][c8+7]=siluf(a11.w);
  __syncthreads();
  a00=*(const float4*)(b2+c8); a01=*(const float4*)(b2+c8+4);
  a10=a00; a11=a01;
  for(int kt=0;kt<8;kt++){
    { const float* src=w2+(size_t)(kt*16+ty)*128+c8;
      *(float4*)&wt[ty][c8]  =*(const float4*)src;
      *(float4*)&wt[ty][c8+4]=*(const float4*)(src+4); }
    __syncthreads();
    #pragma unroll
    for(int kk=0;kk<16;kk++){
      int k=kt*16+kk;
      float m0=t1[n0][k], m1=t1[n1][k];
      float4 wa=*(float4*)&wt[kk][c8], wb=*(float4*)&wt[kk][c8+4];
      a00.x+=m0*wa.x; a00.y+=m0*wa.y; a00.z+=m0*wa.z; a00.w+=m0*wa.w;
      a01.x+=m0*wb.x; a01.y+=m0*wb.y; a01.z+=m0*wb.z; a01.w+=m0*wb.w;
      a10.x+=m1*wa.x; a10.y+=m1*wa.y; a10.z+=m1*wa.z; a10.w+=m1*wa.w;
      a11.x+=m1*wb.x; a11.y+=m1*wb.y; a11.z+=m1*wb.z; a11.w+=m1*wb.w;
    }
    __syncthreads();
  }
  int gn0=g0+n0, gn1=g0+n1;
  if(gn0<NN){ *(float4*)(h+(size_t)gn0*128+c8)=a00; *(float4*)(h+(size_t)gn0*128+c8+4)=a01; }
  if(gn1<NN){ *(float4*)(h+(size_t)gn1*128+c8)=a10; *(float4*)(h+(size_t)gn1*128+c8+4)=a11; }
}

// B-fragment loads from bf16 LDS, generic stride (shorts); kbase dword-aligned
__device__ __forceinline__ short8 ldB(const unsigned short* base, int row, int kbase){
  const unsigned short* tp = base + row*TSTR + kbase;
  union { unsigned int u[4]; short8 s; } r;
  r.u[0] = *(const unsigned int*)(tp);
  r.u[1] = *(const unsigned int*)(tp+2);
  r.u[2] = *(const unsigned int*)(tp+4);
  r.u[3] = *(const unsigned int*)(tp+6);
  return r.s;
}
__device__ __forceinline__ short8 ldBs(const unsigned short* base, int row, int kbase, int stride){
  const unsigned short* tp = base + row*stride + kbase;
  union { unsigned int u[4]; short8 s; } r;
  r.u[0] = *(const unsigned int*)(tp);
  r.u[1] = *(const unsigned int*)(tp+2);
  r.u[2] = *(const unsigned int*)(tp+4);
  r.u[3] = *(const unsigned int*)(tp+6);
  return r.s;
}

// ==== MFMA k_pre: pa|pb = h @ [W1_pa|W1_pb] (+b1 on pa) — used once for layer 0 ====
__global__ void __launch_bounds__(256)
k_preM(const float* __restrict__ h, const float* __restrict__ b1,
       const unsigned short* __restrict__ blob,
       float* __restrict__ pa, float* __restrict__ pb){
  __shared__ unsigned short cHi[32*130], cLo[32*130];
  int tid=threadIdx.x;
  int g0=blockIdx.x*32;
  { int n=tid>>3, c0=(tid&7)*16;
    int gn=g0+n; if(gn>=NN) gn=NN-1;
    const float* src=h+(size_t)gn*128+c0;
    #pragma unroll
    for(int q=0;q<4;q++){
      float4 v=*(const float4*)(src+q*4);
      unsigned h01,h23,l01,l23;
      split4(v.x,v.y,v.z,v.w,h01,h23,l01,l23);
      int o=n*130+c0+q*4;
      *(unsigned*)&cHi[o]=h01; *(unsigned*)&cHi[o+2]=h23;
      *(unsigned*)&cLo[o]=l01; *(unsigned*)&cLo[o+2]=l23;
    } }
  __syncthreads();
  int wl=tid>>6, lane=tid&63, q4=lane>>4, l15=lane&15;
  const short8* fr = (const short8*)blob;
  #pragma unroll
  for(int mi=0;mi<2;mi++){
    int mt = wl + mi*4;
    short8 A[4][2];
    #pragma unroll
    for(int kt=0;kt<4;kt++){
      A[kt][0]=fr[(size_t)((mt*4+kt)*2+0)*64+lane];
      A[kt][1]=fr[(size_t)((mt*4+kt)*2+1)*64+lane];
    }
    f32x4 acc0={0.f,0.f,0.f,0.f}, acc1=acc0;
    #pragma unroll
    for(int kt=0;kt<4;kt++){
      short8 bh0=ldBs(cHi, l15,    kt*32+q4*8, 130);
      short8 bl0=ldBs(cLo, l15,    kt*32+q4*8, 130);
      short8 bh1=ldBs(cHi, 16+l15, kt*32+q4*8, 130);
      short8 bl1=ldBs(cLo, 16+l15, kt*32+q4*8, 130);
      acc0=MFMA_BF16(A[kt][0],bh0,acc0); acc0=MFMA_BF16(A[kt][0],bl0,acc0); acc0=MFMA_BF16(A[kt][1],bh0,acc0);
      acc1=MFMA_BF16(A[kt][0],bh1,acc1); acc1=MFMA_BF16(A[kt][0],bl1,acc1); acc1=MFMA_BF16(A[kt][1],bh1,acc1);
    }
    int m0=mt*16+q4*4;
    float4 bias = (mt<4) ? *(const float4*)(b1+m0) : make_float4(0,0,0,0);
    #pragma unroll
    for(int nt=0;nt<2;nt++){
      f32x4 c = nt ? acc1 : acc0;
      int node=g0+nt*16+l15;
      if(node<NN){
        float4 o = make_float4(c[0]+bias.x, c[1]+bias.y, c[2]+bias.z, c[3]+bias.w);
        if (mt<4) *(float4*)(pa+(size_t)node*64+m0)=o;
        else      *(float4*)(pb+(size_t)node*64+(m0-64))=o;
      }
    }
  }
}

// ==== fused edge kernel — R5 version (LDS weight staging) ====
__global__ void __launch_bounds__(512,4)
k_edge2(const int2* __restrict__ sd, const unsigned short* __restrict__ efb,
        const float* __restrict__ x,
        const float* __restrict__ pa, const float* __restrict__ pb,
        const int* __restrict__ roff_dst,
        const float* __restrict__ w1,
        const float* __restrict__ b2,
        const float* __restrict__ xb1,
        const float* __restrict__ xw2, const float* __restrict__ xb2,
        const unsigned short* __restrict__ wblob,
        float* __restrict__ agg, float4* __restrict__ cvec){
  __shared__ unsigned short tHi[128*TSTR];
  __shared__ unsigned short tLo[128*TSTR];
  __shared__ unsigned short wlds[40*512];
  __shared__ float sqb[128], dxb[128], dyb[128], dzb[128];
  __shared__ int   sbuf[128], dbuf[128];
  int bid = blockIdx.x;
  int nb = (bid&7)*((int)gridDim.x>>3) + (bid>>3);
  int p0 = nb*EB;
  if (p0 >= NE) return;
  int tid = threadIdx.x;
  int wl = tid>>6, lane = tid&63;
  int q4 = lane>>4, l15 = lane&15;

  float4 st0,st1,st2,st3,st4;
  { const float4* wsrc = (const float4*)wblob;
    st0=wsrc[tid]; st1=wsrc[tid+512]; st2=wsrc[tid+1024]; st3=wsrc[tid+1536]; st4=wsrc[tid+2048]; }

  int tile = nb*8 + wl;
  short8 ebh = {0,0,0,0,0,0,0,0};
  short8 ebl = ebh;
  if (lane < 32){
    const short8* ep = (const short8*)efb + (size_t)tile*64;
    ebh = ep[lane]; ebl = ep[lane+32];
  }

  if (tid < 128){
    int p = p0 + tid;
    int2 sdp = (p<NE) ? sd[p] : make_int2(0,0);
    float dx=0.f, dy=0.f, dz=0.f;
    if (p<NE){
      dx = x[sdp.x*3+0]-x[sdp.y*3+0];
      dy = x[sdp.x*3+1]-x[sdp.y*3+1];
      dz = x[sdp.x*3+2]-x[sdp.y*3+2];
    }
    sbuf[tid]=sdp.x; dbuf[tid]=sdp.y;
    sqb[tid]=dx*dx+dy*dy+dz*dz;
    dxb[tid]=dx; dyb[tid]=dy; dzb[tid]=dz;
  }
  { float4* wd = (float4*)wlds;
    wd[tid]=st0; wd[tid+512]=st1; wd[tid+1024]=st2; wd[tid+1536]=st3; wd[tid+2048]=st4; }
  __syncthreads();

  int rowb = 16*wl + l15;
  int s = sbuf[rowb], d = dbuf[rowb];
  float sqv = sqb[rowb];
  const short8* wfr = (const short8*)wlds;

  // ---- GEMM0 + exact fp32 epilogue, silu, trunc-split -> LDS ----
  #pragma unroll
  for(int mt=0;mt<4;mt++){
    short8 ah = wfr[(2*mt+0)*64+lane];
    short8 al = wfr[(2*mt+1)*64+lane];
    f32x4 c = {0.f,0.f,0.f,0.f};
    c = MFMA_BF16(ah, ebh, c);
    c = MFMA_BF16(ah, ebl, c);
    c = MFMA_BF16(al, ebh, c);
    float4 Ai = *(const float4*)(pa + (size_t)s*64 + mt*16 + q4*4);
    float4 Bi = *(const float4*)(pb + (size_t)d*64 + mt*16 + q4*4);
    float4 Wq = *(const float4*)(w1 + 256*64 + mt*16 + q4*4);
    float v0 = siluf(c[0] + Ai.x + Bi.x + sqv*Wq.x);
    float v1 = siluf(c[1] + Ai.y + Bi.y + sqv*Wq.y);
    float v2 = siluf(c[2] + Ai.z + Bi.z + sqv*Wq.z);
    float v3 = siluf(c[3] + Ai.w + Bi.w + sqv*Wq.w);
    unsigned h01,h23,l01,l23;
    split4(v0,v1,v2,v3,h01,h23,l01,l23);
    int mo = rowb*TSTR + mt*16 + q4*4;
    *(unsigned*)&tHi[mo]   = h01;
    *(unsigned*)&tHi[mo+2] = h23;
    *(unsigned*)&tLo[mo]   = l01;
    *(unsigned*)&tLo[mo+2] = l23;
  }
  // no barrier: wave reads only its own rows

  // ---- GEMM1: msg = silu(w2^T @ t + b2), repack trunc-split in place ----
  { short8 bh0 = ldB(tHi, rowb, q4*8);
    short8 bh1 = ldB(tHi, rowb, 32 + q4*8);
    short8 bl0 = ldB(tLo, rowb, q4*8);
    short8 bl1 = ldB(tLo, rowb, 32 + q4*8);
    #pragma unroll
    for(int mt=0;mt<4;mt++){
      short8 ah0 = wfr[(8+mt*4+0)*64+lane];
      short8 al0 = wfr[(8+mt*4+1)*64+lane];
      short8 ah1 = wfr[(8+mt*4+2)*64+lane];
      short8 al1 = wfr[(8+mt*4+3)*64+lane];
      f32x4 c = {0.f,0.f,0.f,0.f};
      c = MFMA_BF16(ah0,bh0,c); c = MFMA_BF16(ah0,bl0,c); c = MFMA_BF16(al0,bh0,c);
      c = MFMA_BF16(ah1,bh1,c); c = MFMA_BF16(ah1,bl1,c); c = MFMA_BF16(al1,bh1,c);
      float4 bb = *(const float4*)(b2 + mt*16 + q4*4);
      float v0=siluf(c[0]+bb.x), v1=siluf(c[1]+bb.y), v2=siluf(c[2]+bb.z), v3=siluf(c[3]+bb.w);
      unsigned h01,h23,l01,l23;
      split4(v0,v1,v2,v3,h01,h23,l01,l23);
      int mo = rowb*TSTR + mt*16 + q4*4;
      *(unsigned*)&tHi[mo]   = h01;
      *(unsigned*)&tHi[mo+2] = h23;
      *(unsigned*)&tLo[mo]   = l01;
      *(unsigned*)&tLo[mo+2] = l23;
    } }

  // ---- GEMM2: xh = xw1^T @ msg; w = silu(xh)·xw2 + xb2; stream cvec ----
  { short8 mh0 = ldB(tHi, rowb, q4*8);
    short8 mh1 = ldB(tHi, rowb, 32 + q4*8);
    short8 ml0 = ldB(tLo, rowb, q4*8);
    short8 ml1 = ldB(tLo, rowb, 32 + q4*8);
    float part = 0.f;
    #pragma unroll
    for(int mt=0;mt<4;mt++){
      short8 ah0 = wfr[(24+mt*4+0)*64+lane];
      short8 al0 = wfr[(24+mt*4+1)*64+lane];
      short8 ah1 = wfr[(24+mt*4+2)*64+lane];
      short8 al1 = wfr[(24+mt*4+3)*64+lane];
      f32x4 c = {0.f,0.f,0.f,0.f};
      c = MFMA_BF16(ah0,mh0,c); c = MFMA_BF16(ah0,ml0,c); c = MFMA_BF16(al0,mh0,c);
      c = MFMA_BF16(ah1,mh1,c); c = MFMA_BF16(ah1,ml1,c); c = MFMA_BF16(al1,mh1,c);
      float4 xb  = *(const float4*)(xb1 + mt*16 + q4*4);
      float4 wv4 = *(const float4*)(xw2 + mt*16 + q4*4);
      part += siluf(c[0]+xb.x)*wv4.x + siluf(c[1]+xb.y)*wv4.y
            + siluf(c[2]+xb.z)*wv4.z + siluf(c[3]+xb.w)*wv4.w;
    }
    part += __shfl_xor(part,16);
    part += __shfl_xor(part,32);
    int pw = p0 + rowb;
    if (q4==0 && pw < NE){
      float wv = part + xb2[0];
      cvec[pw] = make_float4(dxb[rowb]*wv, dyb[rowb]*wv, dzb[rowb]*wv, 0.f);
    }
  }
  __syncthreads();                 // msg final (all rows)

  // ---- fused segmented reduction over dst: 2 cols/thread, dword reads ----
  int pend = (p0+EB < NE) ? (p0+EB) : NE;
  int dfirst = sd[p0].y;
  int dlast  = sd[pend-1].y;
  int jj = (tid&31)*2, slot = tid>>5;
  for (int n=dfirst+slot; n<=dlast; n+=16){
    int rs0 = roff_dst[n], re0 = roff_dst[n+1];
    int rs = (rs0 > p0)   ? rs0 : p0;
    int re = (re0 < pend) ? re0 : pend;
    rs -= p0; re -= p0;
    if (re > rs){
      float s0=0.f, s1=0.f;
      for (int r=rs; r<re; r++){
        unsigned dh = *(const unsigned*)&tHi[r*TSTR+jj];
        unsigned dl = *(const unsigned*)&tLo[r*TSTR+jj];
        s0 += __uint_as_float(dh<<16) + __uint_as_float(dl<<16);
        s1 += __uint_as_float(dh&0xFFFF0000u) + __uint_as_float(dl&0xFFFF0000u);
      }
      if (rs0 >= p0 && re0 <= pend){
        float2 o = make_float2(s0,s1);
        *(float2*)&agg[(size_t)n*64+jj] = o;
      } else {
        atomicAdd(&agg[(size_t)n*64+jj], s0);
        atomicAdd(&agg[(size_t)n*64+jj+1], s1);
      }
    }
  }
}

// ---- phase C: 16 lanes per src node; pure sum of precomputed cvec ----
__global__ void k_coordC(const int* __restrict__ roff_src, const int* __restrict__ slist,
                         const float4* __restrict__ cvec, float* __restrict__ cacc){
  int tid=threadIdx.x;
  int grp=tid>>4, sub=tid&15;
  int n = blockIdx.x*16 + grp;
  if (n >= NN) return;
  int s = roff_src[n], e2 = roff_src[n+1];
  float a0=0.f, a1=0.f, a2=0.f;
  for (int p=s+sub; p<e2; p+=16){
    float4 c = cvec[slist[p]];
    a0 += c.x; a1 += c.y; a2 += c.z;
  }
  #pragma unroll
  for(int off=1; off<16; off<<=1){
    a0 += __shfl_xor(a0, off);
    a1 += __shfl_xor(a1, off);
    a2 += __shfl_xor(a2, off);
  }
  if (sub==0){
    cacc[n*3+0]=a0; cacc[n*3+1]=a1; cacc[n*3+2]=a2;
  }
}

// ==== MFMA k_node + fused next-layer pre ====
// After LN, normalized h tile is re-split into cHi/cLo (stride 130) and the
// k_preM GEMM for layer l+1 runs in-kernel, writing pa/pb (skipped last layer).
__global__ void __launch_bounds__(256)
k_nodeM(const float* __restrict__ agg, const float* __restrict__ cacc,
        const float* __restrict__ cntinv,
        const float* __restrict__ hb1, const float* __restrict__ hb2,
        const float* __restrict__ lng, const float* __restrict__ lnb,
        const unsigned short* __restrict__ nbase,
        const unsigned short* __restrict__ nextpre, const float* __restrict__ nb1,
        float* __restrict__ h, float* __restrict__ x,
        float* __restrict__ pa, float* __restrict__ pb){
  __shared__ float hsf[32][132];
  __shared__ unsigned short cHi[32*194], cLo[32*194];
  __shared__ unsigned short t2Hi[32*130], t2Lo[32*130];
  __shared__ float psA[32][8], psB[32][8];
  __shared__ float mu_s[32], rs_s[32];
  int tid=threadIdx.x;
  int g0=blockIdx.x*32;
  { int n=tid>>3, c0=(tid&7)*16;
    int gn=g0+n; if(gn>=NN) gn=NN-1;
    const float* src=h+(size_t)gn*128+c0;
    #pragma unroll
    for(int q=0;q<4;q++){
      float4 v=*(const float4*)(src+q*4);
      *(float4*)&hsf[n][c0+q*4]=v;
      unsigned h01,h23,l01,l23;
      split4(v.x,v.y,v.z,v.w,h01,h23,l01,l23);
      int o=n*194+c0+q*4;
      *(unsigned*)&cHi[o]=h01; *(unsigned*)&cHi[o+2]=h23;
      *(unsigned*)&cLo[o]=l01; *(unsigned*)&cLo[o+2]=l23;
    }
    float ci=cntinv[gn];
    int ca=(tid&7)*8;
    const float* srca=agg+(size_t)gn*64+ca;
    #pragma unroll
    for(int q=0;q<2;q++){
      float4 v=*(const float4*)(srca+q*4);
      unsigned h01,h23,l01,l23;
      split4(v.x*ci,v.y*ci,v.z*ci,v.w*ci,h01,h23,l01,l23);
      int o=n*194+128+ca+q*4;
      *(unsigned*)&cHi[o]=h01; *(unsigned*)&cHi[o+2]=h23;
      *(unsigned*)&cLo[o]=l01; *(unsigned*)&cLo[o+2]=l23;
    } }
  __syncthreads();
  int wl=tid>>6, lane=tid&63, q4=lane>>4, l15=lane&15;
  const short8* f1 = (const short8*)(nbase + 32768);
  const short8* f2 = (const short8*)(nbase + 81920);
  // GEMM1: t = silu(cat @ hw1 + hb1), K=192
  #pragma unroll
  for(int mi=0;mi<2;mi++){
    int mt=wl+mi*4;
    short8 A[6][2];
    #pragma unroll
    for(int kt=0;kt<6;kt++){
      A[kt][0]=f1[(size_t)((mt*6+kt)*2+0)*64+lane];
      A[kt][1]=f1[(size_t)((mt*6+kt)*2+1)*64+lane];
    }
    f32x4 acc0={0.f,0.f,0.f,0.f}, acc1=acc0;
    #pragma unroll
    for(int kt=0;kt<6;kt++){
      short8 bh0=ldBs(cHi, l15,    kt*32+q4*8, 194);
      short8 bl0=ldBs(cLo, l15,    kt*32+q4*8, 194);
      short8 bh1=ldBs(cHi, 16+l15, kt*32+q4*8, 194);
      short8 bl1=ldBs(cLo, 16+l15, kt*32+q4*8, 194);
      acc0=MFMA_BF16(A[kt][0],bh0,acc0); acc0=MFMA_BF16(A[kt][0],bl0,acc0); acc0=MFMA_BF16(A[kt][1],bh0,acc0);
      acc1=MFMA_BF16(A[kt][0],bh1,acc1); acc1=MFMA_BF16(A[kt][0],bl1,acc1); acc1=MFMA_BF16(A[kt][1],bh1,acc1);
    }
    int m0=mt*16+q4*4;
    float4 bias=*(const float4*)(hb1+m0);
    #pragma unroll
    for(int nt=0;nt<2;nt++){
      f32x4 c = nt ? acc1 : acc0;
      int row=nt*16+l15;
      float v0=siluf(c[0]+bias.x), v1=siluf(c[1]+bias.y), v2=siluf(c[2]+bias.z), v3=siluf(c[3]+bias.w);
      unsigned h01,h23,l01,l23;
      split4(v0,v1,v2,v3,h01,h23,l01,l23);
      int mo=row*130+m0;
      *(unsigned*)&t2Hi[mo]=h01; *(unsigned*)&t2Hi[mo+2]=h23;
      *(unsigned*)&t2Lo[mo]=l01; *(unsigned*)&t2Lo[mo+2]=l23;
    }
  }
  __syncthreads();
  // GEMM2: dh = t @ hw2 + hb2; hsf += dh
  #pragma unroll
  for(int mi=0;mi<2;mi++){
    int mt=wl+mi*4;
    short8 A[4][2];
    #pragma unroll
    for(int kt=0;kt<4;kt++){
      A[kt][0]=f2[(size_t)((mt*4+kt)*2+0)*64+lane];
      A[kt][1]=f2[(size_t)((mt*4+kt)*2+1)*64+lane];
    }
    f32x4 acc0={0.f,0.f,0.f,0.f}, acc1=acc0;
    #pragma unroll
    for(int kt=0;kt<4;kt++){
      short8 bh0=ldBs(t2Hi, l15,    kt*32+q4*8, 130);
      short8 bl0=ldBs(t2Lo, l15,    kt*32+q4*8, 130);
      short8 bh1=ldBs(t2Hi, 16+l15, kt*32+q4*8, 130);
      short8 bl1=ldBs(t2Lo, 16+l15, kt*32+q4*8, 130);
      acc0=MFMA_BF16(A[kt][0],bh0,acc0); acc0=MFMA_BF16(A[kt][0],bl0,acc0); acc0=MFMA_BF16(A[kt][1],bh0,acc0);
      acc1=MFMA_BF16(A[kt][0],bh1,acc1); acc1=MFMA_BF16(A[kt][0],bl1,acc1); acc1=MFMA_BF16(A[kt][1],bh1,acc1);
    }
    int m0=mt*16+q4*4;
    float4 bias=*(const float4*)(hb2+m0);
    #pragma unroll
    for(int nt=0;nt<2;nt++){
      f32x4 c = nt ? acc1 : acc0;
      int row=nt*16+l15;
      hsf[row][m0+0]+=c[0]+bias.x;
      hsf[row][m0+1]+=c[1]+bias.y;
      hsf[row][m0+2]+=c[2]+bias.z;
      hsf[row][m0+3]+=c[3]+bias.w;
    }
  }
  __syncthreads();
  // LayerNorm (fp32, exact)
  { int rid=tid>>3, sub=tid&7;
    float sm=0.f, ss=0.f;
    #pragma unroll
    for(int i=0;i<16;i++){ float v=hsf[rid][sub*16+i]; sm+=v; ss+=v*v; }
    psA[rid][sub]=sm; psB[rid][sub]=ss; }
  __syncthreads();
  { int rid=tid>>3, sub=tid&7;
    if(sub==0){
      float sm=0.f, ss=0.f;
      #pragma unroll
      for(int i=0;i<8;i++){ sm+=psA[rid][i]; ss+=psB[rid][i]; }
      float mu=sm*(1.0f/128.0f);
      float var=ss*(1.0f/128.0f)-mu*mu;
      mu_s[rid]=mu; rs_s[rid]=rsqrtf(fmaxf(var,0.0f)+1e-5f);
    } }
  __syncthreads();
  // LN write phase: store h AND re-split normalized tile into cHi/cLo (stride 130)
  { int rid=tid>>3, sub=tid&7;
    int gn=g0+rid;
    bool ok = gn<NN;
    float mu=mu_s[rid], rs=rs_s[rid];
    int c0=sub*16;
    #pragma unroll
    for(int q=0;q<4;q++){
      float4 g4=*(const float4*)(lng+c0+q*4);
      float4 b4=*(const float4*)(lnb+c0+q*4);
      float4 o;
      o.x=(hsf[rid][c0+q*4+0]-mu)*rs*g4.x+b4.x;
      o.y=(hsf[rid][c0+q*4+1]-mu)*rs*g4.y+b4.y;
      o.z=(hsf[rid][c0+q*4+2]-mu)*rs*g4.z+b4.z;
      o.w=(hsf[rid][c0+q*4+3]-mu)*rs*g4.w+b4.w;
      if(ok) *(float4*)(h+(size_t)gn*128+c0+q*4)=o;
      if(nextpre){
        unsigned h01,h23,l01,l23;
        split4(o.x,o.y,o.z,o.w,h01,h23,l01,l23);
        int oo=rid*130+c0+q*4;
        *(unsigned*)&cHi[oo]=h01; *(unsigned*)&cHi[oo+2]=h23;
        *(unsigned*)&cLo[oo]=l01; *(unsigned*)&cLo[oo+2]=l23;
      }
    } }
  if(tid<32){
    int gn=g0+tid;
    if(gn<NN){
      float ci=cntinv[gn];
      x[gn*3+0]+=cacc[gn*3+0]*ci;
      x[gn*3+1]+=cacc[gn*3+1]*ci;
      x[gn*3+2]+=cacc[gn*3+2]*ci;
    }
  }
  // ---- fused next-layer pre: pa|pb = h_new @ [W1_pa|W1_pb] (+nb1 on pa) ----
  if(nextpre){
    __syncthreads();
    const short8* fr = (const short8*)nextpre;
    #pragma unroll
    for(int mi=0;mi<2;mi++){
      int mt = wl + mi*4;
      short8 A[4][2];
      #pragma unroll
      for(int kt=0;kt<4;kt++){
        A[kt][0]=fr[(size_t)((mt*4+kt)*2+0)*64+lane];
        A[kt][1]=fr[(size_t)((mt*4+kt)*2+1)*64+lane];
      }
      f32x4 acc0={0.f,0.f,0.f,0.f}, acc1=acc0;
      #pragma unroll
      for(int kt=0;kt<4;kt++){
        short8 bh0=ldBs(cHi, l15,    kt*32+q4*8, 130);
        short8 bl0=ldBs(cLo, l15,    kt*32+q4*8, 130);
        short8 bh1=ldBs(cHi, 16+l15, kt*32+q4*8, 130);
        short8 bl1=ldBs(cLo, 16+l15, kt*32+q4*8, 130);
        acc0=MFMA_BF16(A[kt][0],bh0,acc0); acc0=MFMA_BF16(A[kt][0],bl0,acc0); acc0=MFMA_BF16(A[kt][1],bh0,acc0);
        acc1=MFMA_BF16(A[kt][0],bh1,acc1); acc1=MFMA_BF16(A[kt][0],bl1,acc1); acc1=MFMA_BF16(A[kt][1],bh1,acc1);
      }
      int m0=mt*16+q4*4;
      float4 bias = (mt<4) ? *(const float4*)(nb1+m0) : make_float4(0,0,0,0);
      #pragma unroll
      for(int nt=0;nt<2;nt++){
        f32x4 c = nt ? acc1 : acc0;
        int node=g0+nt*16+l15;
        if(node<NN){
          float4 o = make_float4(c[0]+bias.x, c[1]+bias.y, c[2]+bias.z, c[3]+bias.w);
          if (mt<4) *(float4*)(pa+(size_t)node*64+m0)=o;
          else      *(float4*)(pb+(size_t)node*64+(m0-64))=o;
        }
      }
    }
  }
}

// ---- readout (unchanged) ----
__device__ __forceinline__ int lowerb(const int* a, int n, int v){
  int lo=0, hi=n;
  while(lo<hi){ int mid=(lo+hi)>>1; if(a[mid]<v) lo=mid+1; else hi=mid; }
  return lo;
}

__global__ void k_readout(const int* __restrict__ batch, const float* __restrict__ h,
                          const float* __restrict__ w1, const float* __restrict__ b1,
                          const float* __restrict__ w2, const float* __restrict__ b2,
                          const float* __restrict__ w3, const float* __restrict__ b3,
                          float* __restrict__ out){
  int g = blockIdx.x;
  int wl = threadIdx.x>>6, lane = threadIdx.x&63;
  __shared__ float part[4][128];
  __shared__ float gh[128];
  __shared__ float r1[128];
  __shared__ float r2[64];
  int start = lowerb(batch, NN, g);
  int end   = lowerb(batch, NN, g+1);
  float s0=0.f, s1=0.f;
  for(int n=start+wl; n<end; n+=4){
    s0 += h[(size_t)n*128+2*lane];
    s1 += h[(size_t)n*128+2*lane+1];
  }
  part[wl][2*lane]=s0; part[wl][2*lane+1]=s1;
  __syncthreads();
  float ci = 1.0f/fmaxf((float)(end-start),1.0f);
  if(wl==0){
    gh[2*lane]   = (part[0][2*lane]+part[1][2*lane]+part[2][2*lane]+part[3][2*lane])*ci;
    gh[2*lane+1] = (part[0][2*lane+1]+part[1][2*lane+1]+part[2][2*lane+1]+part[3][2*lane+1])*ci;
  }
  __syncthreads();
  if(wl==0){
    float a0=b1[2*lane], a1=b1[2*lane+1];
    for(int k=0;k<128;k++){
      float m=gh[k];
      float2 w=((const float2*)(w1+k*128))[lane];
      a0+=m*w.x; a1+=m*w.y;
    }
    r1[2*lane]=siluf(a0); r1[2*lane+1]=siluf(a1);
  }
  __syncthreads();
  if(wl==0){
    float b=b2[lane];
    for(int k=0;k<128;k++) b += r1[k]*w2[k*64+lane];
    r2[lane]=siluf(b);
  }
  __syncthreads();
  if(wl==0 && lane<2){
    float o=b3[lane];
    for(int k=0;k<64;k++) o += r2[k]*w3[k*2+lane];
    out[g*2+lane]=o;
  }
}

extern "C" void kernel_launch(void* const* d_in, const int* in_sizes, int n_in,
                              void* d_out, int out_size, void* d_ws, size_t ws_size,
                              hipStream_t stream){
  const float* nf     = (const float*)d_in[0];
  const float* coords = (const float*)d_in[1];
  const int*   ei     = (const int*)d_in[2];
  const float* ef     = (const float*)d_in[3];
  const int*   batch  = (const int*)d_in[4];

  const float* enc_w1 = (const float*)d_in[5];
  const float* enc_b1 = (const float*)d_in[6];
  const float* enc_w2 = (const float*)d_in[7];
  const float* enc_b2 = (const float*)d_in[8];
  const float* pe_w1  = (const float*)d_in[9];
  const float* pe_b1  = (const float*)d_in[10];
  const float* pe_w2  = (const float*)d_in[11];
  const float* pe_b2  = (const float*)d_in[12];
  const float* ph_w1  = (const float*)d_in[13];
  const float* ph_b1  = (const float*)d_in[14];
  const float* ph_w2  = (const float*)d_in[15];
  const float* ph_b2  = (const float*)d_in[16];
  const float* px_w1  = (const float*)d_in[17];
  const float* px_b1  = (const float*)d_in[18];
  const float* px_w2  = (const float*)d_in[19];
  const float* px_b2  = (const float*)d_in[20];
  const float* ln_g   = (const float*)d_in[21];
  const float* ln_b   = (const float*)d_in[22];
  const float* ro_w1  = (const float*)d_in[23];
  const float* ro_b1  = (const float*)d_in[24];
  const float* ro_w2  = (const float*)d_in[25];
  const float* ro_b2  = (const float*)d_in[26];
  const float* ro_w3  = (const float*)d_in[27];
  const float* ro_b3  = (const float*)d_in[28];

  char* wsb = (char*)d_ws;
  size_t off = 0;
  auto alloc_f = [&](size_t nfl)->float*{ float* p=(float*)(wsb+off); off+=nfl*4; return p; };
  auto alloc_i = [&](size_t nin)->int*  { int*   p=(int*)(wsb+off);   off+=nin*4; return p; };

  float* h      = alloc_f((size_t)NN*128);
  float* x      = alloc_f((size_t)NN*3);
  float* agg    = alloc_f((size_t)NN*64);
  float* cacc   = alloc_f((size_t)NN*3);
  float* cntinv = alloc_f(NN);
  float* pa     = alloc_f((size_t)NN*64);
  float* pb     = alloc_f((size_t)NN*64);
  float4* cvec  = (float4*)alloc_f((size_t)NE*4);        // 16 MB streaming per layer
  unsigned short* efb = (unsigned short*)alloc_f((size_t)NE*16 + 2048); // 64 MB + tail pad
  int2*  sd_s   = (int2*)alloc_i((size_t)NE*2);
  unsigned short* wblob = (unsigned short*)alloc_i((size_t)NL*40*512/2);   // 245,760 B
  unsigned short* nblob = (unsigned short*)alloc_i((size_t)NL*224*512/2);  // 1,376,256 B
  int* roff_dst = alloc_i(NN+1);
  int* roff_src = alloc_i(NN+1);
  int* dlist    = alloc_i(NE);
  int* slist    = alloc_i(NE);
  int* bsum     = alloc_i(256);
  int* bbase    = alloc_i(256);
  int* cnt_dst  = alloc_i(NN);   // cnt_dst..cur_src contiguous -> one memset
  int* cnt_src  = alloc_i(NN);
  int* cur_dst  = alloc_i(NN);
  int* cur_src  = alloc_i(NN);

  hipMemsetAsync(cnt_dst, 0, (size_t)4*NN*sizeof(int), stream);
  k_degrees<<<(NE+255)/256,256,0,stream>>>(ei, cnt_dst, cnt_src);
  k_scan1<<<NB_SCAN,256,0,stream>>>(cnt_dst, roff_dst, bsum);
  k_scan2<<<1,256,0,stream>>>(bsum, bbase, roff_dst);
  k_scan3<<<NB_SCAN,256,0,stream>>>(roff_dst, bbase);
  k_scan1<<<NB_SCAN,256,0,stream>>>(cnt_src, roff_src, bsum);
  k_scan2<<<1,256,0,stream>>>(bsum, bbase, roff_src);
  k_scan3<<<NB_SCAN,256,0,stream>>>(roff_src, bbase);
  k_fill<<<(NE+255)/256,256,0,stream>>>(ei, roff_dst, roff_src, cur_dst, cur_src, dlist, slist);
  k_gather<<<(NE+255)/256,256,0,stream>>>(ei, ef, dlist, sd_s, efb);
  k_prep<<<(NN+255)/256,256,0,stream>>>(coords, cnt_dst, x, cntinv);
  k_wprep<<<(NL*40*64+255)/256,256,0,stream>>>(pe_w1, pe_w2, px_w1, wblob);
  k_wprep2<<<(NL*224*64+255)/256,256,0,stream>>>(pe_w1, ph_w1, ph_w2, nblob);
  k_encoder<<<(NN+31)/32,256,0,stream>>>(nf, enc_w1, enc_b1, enc_w2, enc_b2, h);

  int G  = (NE+EB-1)/EB;
  int G8 = ((G+7)/8)*8;

  // layer-0 pre (encoder output -> pa/pb); later layers fused into k_nodeM
  k_preM<<<(NN+31)/32,256,0,stream>>>(h, pe_b1, nblob, pa, pb);

  for(int l=0;l<NL;l++){
    const unsigned short* nbl = nblob + (size_t)l*224*512;
    hipMemsetAsync(agg, 0, (size_t)NN*64*sizeof(float), stream);
    k_edge2<<<G8,512,0,stream>>>(sd_s, efb, x, pa, pb, roff_dst,
        pe_w1+(size_t)l*273*64,
        pe_b2+l*64,
        px_b1+l*64,
        px_w2+l*64, px_b2+l,
        wblob + (size_t)l*40*512,
        agg, cvec);
    k_coordC<<<(NN+15)/16,256,0,stream>>>(roff_src, slist, cvec, cacc);
    const unsigned short* nxt = (l+1<NL) ? (nblob + (size_t)(l+1)*224*512) : (const unsigned short*)nullptr;
    const float* nb1 = (l+1<NL) ? (pe_b1 + (size_t)(l+1)*64) : pe_b1;
    k_nodeM<<<(NN+31)/32,256,0,stream>>>(agg, cacc, cntinv,
        ph_b1+l*128, ph_b2+l*128,
        ln_g+l*128, ln_b+l*128, nbl,
        nxt, nb1, h, x, pa, pb);
  }

  k_readout<<<NG,256,0,stream>>>(batch, h,
      ro_w1, ro_b1, ro_w2, ro_b2, ro_w3, ro_b3, (float*)d_out);
}

// Round 8
// 1766.629 us; speedup vs baseline: 1.1566x; 1.0200x over previous
//
#include <hip/hip_runtime.h>
#include <hip/hip_bf16.h>

#define NN 50000
#define NE 1000000
#define NG 256
#define NL 6
#define NB_SCAN 196   // ceil(NN/256)
#define EB 128        // edges per block in k_edge2
#define TSTR 66       // bf16 stride per LDS row in k_edge2 (132 B; conflict-free)

typedef float v2f __attribute__((ext_vector_type(2)));
typedef short short8 __attribute__((ext_vector_type(8)));   // 8 bf16 (4 VGPRs) MFMA frag
typedef float f32x4 __attribute__((ext_vector_type(4)));    // MFMA accum

#define MFMA_BF16(a,b,c) __builtin_amdgcn_mfma_f32_16x16x32_bf16(a,b,c,0,0,0)

// silu via hardware rcp (v_rcp_f32, ~1e-7 rel err)
__device__ __forceinline__ float siluf(float v){
  return v * __builtin_amdgcn_rcpf(1.0f + __expf(-v));
}

// bf16 helpers (RNE — used for WEIGHT prep only; activations use trunc-split below)
__device__ __forceinline__ unsigned f2bf(float x){
  unsigned u = __float_as_uint(x);
  return (u + 0x7FFFu + ((u>>16)&1u)) >> 16;
}
__device__ __forceinline__ float bf2f(unsigned h){
  return __uint_as_float(h<<16);
}

// pack hi16(a) | hi16(b)<<16 in ONE v_perm_b32
__device__ __forceinline__ unsigned pkhi(unsigned a, unsigned b){
  return __builtin_amdgcn_perm(b, a, 0x07060302u);
}
// trunc-split 4 values into packed bf16 hi pairs + lo (trunc of exact residual) pairs.
__device__ __forceinline__ void split4(float v0,float v1,float v2,float v3,
                                       unsigned &h01, unsigned &h23,
                                       unsigned &l01, unsigned &l23){
  unsigned u0=__float_as_uint(v0),u1=__float_as_uint(v1);
  unsigned u2=__float_as_uint(v2),u3=__float_as_uint(v3);
  h01=pkhi(u0,u1); h23=pkhi(u2,u3);
  float r0=v0-__uint_as_float(u0&0xFFFF0000u);
  float r1=v1-__uint_as_float(u1&0xFFFF0000u);
  float r2=v2-__uint_as_float(u2&0xFFFF0000u);
  float r3=v3-__uint_as_float(u3&0xFFFF0000u);
  l01=pkhi(__float_as_uint(r0),__float_as_uint(r1));
  l23=pkhi(__float_as_uint(r2),__float_as_uint(r3));
}

// ---- degree counts (dst + src) ----
__global__ void k_degrees(const int* __restrict__ ei, int* __restrict__ cnt_dst,
                          int* __restrict__ cnt_src){
  int e = blockIdx.x*256 + threadIdx.x;
  if (e<NE){
    atomicAdd(&cnt_dst[ei[NE+e]], 1);
    atomicAdd(&cnt_src[ei[e]], 1);
  }
}

// ---- hierarchical scan ----
__global__ void k_scan1(const int* __restrict__ cnt, int* __restrict__ roff,
                        int* __restrict__ bsum){
  __shared__ int sd[256];
  int t=threadIdx.x; int i=blockIdx.x*256+t;
  int v=(i<NN)?cnt[i]:0;
  sd[t]=v; __syncthreads();
  #pragma unroll
  for(int off=1;off<256;off<<=1){
    int xv=(t>=off)?sd[t-off]:0; __syncthreads();
    sd[t]+=xv; __syncthreads();
  }
  if(i<NN) roff[i]=sd[t]-v;
  if(t==255) bsum[blockIdx.x]=sd[t];
}
__global__ void k_scan2(const int* __restrict__ bsum, int* __restrict__ bbase,
                        int* __restrict__ roff){
  __shared__ int sd[256];
  int t=threadIdx.x;
  int v=(t<NB_SCAN)?bsum[t]:0;
  sd[t]=v; __syncthreads();
  #pragma unroll
  for(int off=1;off<256;off<<=1){
    int xv=(t>=off)?sd[t-off]:0; __syncthreads();
    sd[t]+=xv; __syncthreads();
  }
  if(t<NB_SCAN) bbase[t]=sd[t]-v;
  if(t==255) roff[NN]=sd[t];
}
__global__ void k_scan3(int* __restrict__ roff, const int* __restrict__ bbase){
  int i=blockIdx.x*256+threadIdx.x;
  if(i<NN) roff[i]+=bbase[blockIdx.x];
}

// ---- scatter-fill: dlist = edge ids dst-sorted; slist = dst-sorted POSITIONS per src ----
__global__ void k_fill(const int* __restrict__ ei,
                       const int* __restrict__ roff_dst, const int* __restrict__ roff_src,
                       int* __restrict__ cur_dst, int* __restrict__ cur_src,
                       int* __restrict__ dlist, int* __restrict__ slist){
  int e = blockIdx.x*256 + threadIdx.x;
  if (e<NE){
    int d = ei[NE+e];
    int pd = roff_dst[d] + atomicAdd(&cur_dst[d],1);
    dlist[pd] = e;
    int s = ei[e];
    int ps = roff_src[s] + atomicAdd(&cur_src[s],1);
    slist[ps] = pd;
  }
}

// ---- one-time gather into dst-sorted order + ef -> B-fragment bf16 hi/lo tiles ----
__global__ void k_gather(const int* __restrict__ ei, const float* __restrict__ ef,
                         const int* __restrict__ dlist,
                         int2* __restrict__ sd_s, unsigned short* __restrict__ efb){
  int p = blockIdx.x*256 + threadIdx.x;
  if (p<NE){
    int e = dlist[p];
    sd_s[p] = make_int2(ei[e], ei[NE+e]);
    int tile = p>>4, l15 = p&15;
    size_t hb = (size_t)tile*512 + (size_t)l15*8;
    const float4* src = (const float4*)(ef + (size_t)e*16);
    #pragma unroll
    for(int q=0;q<4;q++){
      float4 v = src[q];
      float vv[4] = {v.x, v.y, v.z, v.w};
      #pragma unroll
      for(int r=0;r<4;r++){
        int k = q*4+r;
        unsigned h  = f2bf(vv[r]);
        unsigned lo = f2bf(vv[r]-bf2f(h));
        size_t o = hb + (size_t)(k>>3)*128 + (k&7);
        efb[o]     = (unsigned short)h;
        efb[o+256] = (unsigned short)lo;
      }
    }
  }
}

// ---- init coords + 1/max(indeg,1) ----
__global__ void k_prep(const float* __restrict__ coords,
                       const int* __restrict__ cnt,
                       float* __restrict__ x, float* __restrict__ cntinv){
  int n = blockIdx.x*256+threadIdx.x;
  if (n<NN){
    x[n*3+0]=coords[n*3+0];
    x[n*3+1]=coords[n*3+1];
    x[n*3+2]=coords[n*3+2];
    cntinv[n]=1.0f/fmaxf((float)cnt[n],1.0f);
  }
}

// ---- one-time weight prep: edge-kernel blobs (RNE hi/lo) ----
__global__ void k_wprep(const float* __restrict__ w1full, const float* __restrict__ w2,
                        const float* __restrict__ xw1,
                        unsigned short* __restrict__ blob){
  int t = blockIdx.x*256 + threadIdx.x;
  if (t >= NL*40*64) return;
  int lane = t & 63;
  int f = (t>>6) % 40;
  int l = t / (40*64);
  int m, hl;
  unsigned short* out = blob + (size_t)t*8;
  if (f < 8){
    int mt = f>>1; hl = f&1;
    m = mt*16 + (lane&15);
    int kb = (lane>>4)*8;
    #pragma unroll
    for(int j=0;j<8;j++){
      int k = kb + j;
      float v = (k<16) ? w1full[(size_t)l*273*64 + (size_t)(257+k)*64 + m] : 0.f;
      unsigned h = f2bf(v);
      if (hl) h = f2bf(v - bf2f(h));
      out[j] = (unsigned short)h;
    }
  } else {
    int fi = (f<24) ? (f-8) : (f-24);
    const float* W = ((f<24) ? w2 : xw1) + (size_t)l*4096;
    int mt = fi>>2, kt = (fi>>1)&1; hl = fi&1;
    m = mt*16 + (lane&15);
    int kb = kt*32 + (lane>>4)*8;
    #pragma unroll
    for(int j=0;j<8;j++){
      float v = W[(size_t)(kb+j)*64 + m];
      unsigned h = f2bf(v);
      if (hl) h = f2bf(v - bf2f(h));
      out[j] = (unsigned short)h;
    }
  }
}

// ---- one-time weight prep: node-side blobs (RNE hi/lo) ----
__global__ void k_wprep2(const float* __restrict__ pw1, const float* __restrict__ hw1,
                         const float* __restrict__ hw2, unsigned short* __restrict__ blob){
  int t = blockIdx.x*256 + threadIdx.x;
  if (t >= NL*224*64) return;
  int lane = t & 63;
  int f = (t>>6) % 224;
  int l = t / (224*64);
  int m15 = lane & 15, kq = (lane>>4)*8;
  unsigned short* out = blob + (size_t)t*8;
  if (f < 64){
    int mt = f>>3, kt = (f>>1)&3, hl = f&1;
    int m = mt*16 + m15;
    const float* W = pw1 + (size_t)l*273*64;
    #pragma unroll
    for(int j=0;j<8;j++){
      int k = kt*32 + kq + j;
      float v = (m<64) ? W[(size_t)k*64 + m] : W[(size_t)(128+k)*64 + (m-64)];
      unsigned hb = f2bf(v);
      if (hl) hb = f2bf(v - bf2f(hb));
      out[j] = (unsigned short)hb;
    }
  } else if (f < 160){
    int fi = f - 64;
    int mt = fi/12, r = fi%12, kt = r>>1, hl = r&1;
    int m = mt*16 + m15;
    const float* W = hw1 + (size_t)l*192*128;
    #pragma unroll
    for(int j=0;j<8;j++){
      int k = kt*32 + kq + j;
      float v = W[(size_t)k*128 + m];
      unsigned hb = f2bf(v);
      if (hl) hb = f2bf(v - bf2f(hb));
      out[j] = (unsigned short)hb;
    }
  } else {
    int fi = f - 160;
    int mt = fi>>3, kt = (fi>>1)&3, hl = fi&1;
    int m = mt*16 + m15;
    const float* W = hw2 + (size_t)l*128*128;
    #pragma unroll
    for(int j=0;j<8;j++){
      int k = kt*32 + kq + j;
      float v = W[(size_t)k*128 + m];
      unsigned hb = f2bf(v);
      if (hl) hb = f2bf(v - bf2f(hb));
      out[j] = (unsigned short)hb;
    }
  }
}

// ==== tiled encoder (unchanged) ====
__global__ void __launch_bounds__(256)
k_encoder(const float* __restrict__ nf,
          const float* __restrict__ w1, const float* __restrict__ b1,
          const float* __restrict__ w2, const float* __restrict__ b2,
          float* __restrict__ h){
  __shared__ float in1[32][17];
  __shared__ float t1[32][129];
  __shared__ float wt[16][136];
  int tid=threadIdx.x;
  int g0=blockIdx.x*32;
  int ty=tid>>4, tx=tid&15;
  int n0=ty*2, n1=ty*2+1;
  { int n=tid>>3, c=(tid&7)*2;
    int gn=g0+n; if(gn>=NN) gn=NN-1;
    float2 v=*(const float2*)(nf+(size_t)gn*16+c);
    in1[n][c]=v.x; in1[n][c+1]=v.y; }
  { int c=tx*8;
    const float* src=w1+(size_t)ty*128+c;
    *(float4*)&wt[ty][c]  =*(const float4*)src;
    *(float4*)&wt[ty][c+4]=*(const float4*)(src+4); }
  __syncthreads();
  float4 a00,a01,a10,a11;
  a00=*(const float4*)(b1+tx*8); a01=*(const float4*)(b1+tx*8+4);
  a10=a00; a11=a01;
  #pragma unroll
  for(int k=0;k<16;k++){
    float m0=in1[n0][k], m1=in1[n1][k];
    float4 wa=*(float4*)&wt[k][tx*8], wb=*(float4*)&wt[k][tx*8+4];
    a00.x+=m0*wa.x; a00.y+=m0*wa.y; a00.z+=m0*wa.z; a00.w+=m0*wa.w;
    a01.x+=m0*wb.x; a01.y+=m0*wb.y; a01.z+=m0*wb.z; a01.w+=m0*wb.w;
    a10.x+=m1*wa.x; a10.y+=m1*wa.y; a10.z+=m1*wa.z; a10.w+=m1*wa.w;
    a11.x+=m1*wb.x; a11.y+=m1*wb.y; a11.z+=m1*wb.z; a11.w+=m1*wb.w;
  }
  int c8=tx*8;
  t1[n0][c8+0]=siluf(a00.x); t1[n0][c8+1]=siluf(a00.y); t1[n0][c8+2]=siluf(a00.z); t1[n0][c8+3]=siluf(a00.w);
  t1[n0][c8+4]=siluf(a01.x); t1[n0][c8+5]=siluf(a01.y); t1[n0][c8+6]=siluf(a01.z); t1[n0][c8+7]=siluf(a01.w);
  t1[n1][c8+0]=siluf(a10.x); t1[n1][c8+1]=siluf(a10.y); t1[n1][c8+2]=siluf(a10.z); t1[n1][c8+3]=siluf(a10.w);
  t1[n1][c8+4]=siluf(a11.x); t1[n1][c8+5]=siluf(a11.y); t1[n1][c8+6]=siluf(a11.z); t1[n1][c8+7]=siluf(a11.w);
  __syncthreads();
  a00=*(const float4*)(b2+c8); a01=*(const float4*)(b2+c8+4);
  a10=a00; a11=a01;
  for(int kt=0;kt<8;kt++){
    { const float* src=w2+(size_t)(kt*16+ty)*128+c8;
      *(float4*)&wt[ty][c8]  =*(const float4*)src;
      *(float4*)&wt[ty][c8+4]=*(const float4*)(src+4); }
    __syncthreads();
    #pragma unroll
    for(int kk=0;kk<16;kk++){
      int k=kt*16+kk;
      float m0=t1[n0][k], m1=t1[n1][k];
      float4 wa=*(float4*)&wt[kk][c8], wb=*(float4*)&wt[kk][c8+4];
      a00.x+=m0*wa.x; a00.y+=m0*wa.y; a00.z+=m0*wa.z; a00.w+=m0*wa.w;
      a01.x+=m0*wb.x; a01.y+=m0*wb.y; a01.z+=m0*wb.z; a01.w+=m0*wb.w;
      a10.x+=m1*wa.x; a10.y+=m1*wa.y; a10.z+=m1*wa.z; a10.w+=m1*wa.w;
      a11.x+=m1*wb.x; a11.y+=m1*wb.y; a11.z+=m1*wb.z; a11.w+=m1*wb.w;
    }
    __syncthreads();
  }
  int gn0=g0+n0, gn1=g0+n1;
  if(gn0<NN){ *(float4*)(h+(size_t)gn0*128+c8)=a00; *(float4*)(h+(size_t)gn0*128+c8+4)=a01; }
  if(gn1<NN){ *(float4*)(h+(size_t)gn1*128+c8)=a10; *(float4*)(h+(size_t)gn1*128+c8+4)=a11; }
}

// B-fragment loads from bf16 LDS, generic stride (shorts); kbase dword-aligned
__device__ __forceinline__ short8 ldB(const unsigned short* base, int row, int kbase){
  const unsigned short* tp = base + row*TSTR + kbase;
  union { unsigned int u[4]; short8 s; } r;
  r.u[0] = *(const unsigned int*)(tp);
  r.u[1] = *(const unsigned int*)(tp+2);
  r.u[2] = *(const unsigned int*)(tp+4);
  r.u[3] = *(const unsigned int*)(tp+6);
  return r.s;
}
__device__ __forceinline__ short8 ldBs(const unsigned short* base, int row, int kbase, int stride){
  const unsigned short* tp = base + row*stride + kbase;
  union { unsigned int u[4]; short8 s; } r;
  r.u[0] = *(const unsigned int*)(tp);
  r.u[1] = *(const unsigned int*)(tp+2);
  r.u[2] = *(const unsigned int*)(tp+4);
  r.u[3] = *(const unsigned int*)(tp+6);
  return r.s;
}

// ==== MFMA k_pre: pa|pb = h @ [W1_pa|W1_pb] (+b1 on pa) — used once for layer 0 ====
__global__ void __launch_bounds__(256)
k_preM(const float* __restrict__ h, const float* __restrict__ b1,
       const unsigned short* __restrict__ blob,
       float* __restrict__ pa, float* __restrict__ pb){
  __shared__ unsigned short cHi[32*130], cLo[32*130];
  int tid=threadIdx.x;
  int g0=blockIdx.x*32;
  { int n=tid>>3, c0=(tid&7)*16;
    int gn=g0+n; if(gn>=NN) gn=NN-1;
    const float* src=h+(size_t)gn*128+c0;
    #pragma unroll
    for(int q=0;q<4;q++){
      float4 v=*(const float4*)(src+q*4);
      unsigned h01,h23,l01,l23;
      split4(v.x,v.y,v.z,v.w,h01,h23,l01,l23);
      int o=n*130+c0+q*4;
      *(unsigned*)&cHi[o]=h01; *(unsigned*)&cHi[o+2]=h23;
      *(unsigned*)&cLo[o]=l01; *(unsigned*)&cLo[o+2]=l23;
    } }
  __syncthreads();
  int wl=tid>>6, lane=tid&63, q4=lane>>4, l15=lane&15;
  const short8* fr = (const short8*)blob;
  #pragma unroll
  for(int mi=0;mi<2;mi++){
    int mt = wl + mi*4;
    short8 A[4][2];
    #pragma unroll
    for(int kt=0;kt<4;kt++){
      A[kt][0]=fr[(size_t)((mt*4+kt)*2+0)*64+lane];
      A[kt][1]=fr[(size_t)((mt*4+kt)*2+1)*64+lane];
    }
    f32x4 acc0={0.f,0.f,0.f,0.f}, acc1=acc0;
    #pragma unroll
    for(int kt=0;kt<4;kt++){
      short8 bh0=ldBs(cHi, l15,    kt*32+q4*8, 130);
      short8 bl0=ldBs(cLo, l15,    kt*32+q4*8, 130);
      short8 bh1=ldBs(cHi, 16+l15, kt*32+q4*8, 130);
      short8 bl1=ldBs(cLo, 16+l15, kt*32+q4*8, 130);
      acc0=MFMA_BF16(A[kt][0],bh0,acc0); acc0=MFMA_BF16(A[kt][0],bl0,acc0); acc0=MFMA_BF16(A[kt][1],bh0,acc0);
      acc1=MFMA_BF16(A[kt][0],bh1,acc1); acc1=MFMA_BF16(A[kt][0],bl1,acc1); acc1=MFMA_BF16(A[kt][1],bh1,acc1);
    }
    int m0=mt*16+q4*4;
    float4 bias = (mt<4) ? *(const float4*)(b1+m0) : make_float4(0,0,0,0);
    #pragma unroll
    for(int nt=0;nt<2;nt++){
      f32x4 c = nt ? acc1 : acc0;
      int node=g0+nt*16+l15;
      if(node<NN){
        float4 o = make_float4(c[0]+bias.x, c[1]+bias.y, c[2]+bias.z, c[3]+bias.w);
        if (mt<4) *(float4*)(pa+(size_t)node*64+m0)=o;
        else      *(float4*)(pb+(size_t)node*64+(m0-64))=o;
      }
    }
  }
}

// ==== fused edge kernel — R5 version (LDS weight staging) ====
__global__ void __launch_bounds__(512,4)
k_edge2(const int2* __restrict__ sd, const unsigned short* __restrict__ efb,
        const float* __restrict__ x,
        const float* __restrict__ pa, const float* __restrict__ pb,
        const int* __restrict__ roff_dst,
        const float* __restrict__ w1,
        const float* __restrict__ b2,
        const float* __restrict__ xb1,
        const float* __restrict__ xw2, const float* __restrict__ xb2,
        const unsigned short* __restrict__ wblob,
        float* __restrict__ agg, float4* __restrict__ cvec){
  __shared__ unsigned short tHi[128*TSTR];
  __shared__ unsigned short tLo[128*TSTR];
  __shared__ unsigned short wlds[40*512];
  __shared__ float sqb[128], dxb[128], dyb[128], dzb[128];
  __shared__ int   sbuf[128], dbuf[128];
  int bid = blockIdx.x;
  int nb = (bid&7)*((int)gridDim.x>>3) + (bid>>3);
  int p0 = nb*EB;
  if (p0 >= NE) return;
  int tid = threadIdx.x;
  int wl = tid>>6, lane = tid&63;
  int q4 = lane>>4, l15 = lane&15;

  float4 st0,st1,st2,st3,st4;
  { const float4* wsrc = (const float4*)wblob;
    st0=wsrc[tid]; st1=wsrc[tid+512]; st2=wsrc[tid+1024]; st3=wsrc[tid+1536]; st4=wsrc[tid+2048]; }

  int tile = nb*8 + wl;
  short8 ebh = {0,0,0,0,0,0,0,0};
  short8 ebl = ebh;
  if (lane < 32){
    const short8* ep = (const short8*)efb + (size_t)tile*64;
    ebh = ep[lane]; ebl = ep[lane+32];
  }

  if (tid < 128){
    int p = p0 + tid;
    int2 sdp = (p<NE) ? sd[p] : make_int2(0,0);
    float dx=0.f, dy=0.f, dz=0.f;
    if (p<NE){
      dx = x[sdp.x*3+0]-x[sdp.y*3+0];
      dy = x[sdp.x*3+1]-x[sdp.y*3+1];
      dz = x[sdp.x*3+2]-x[sdp.y*3+2];
    }
    sbuf[tid]=sdp.x; dbuf[tid]=sdp.y;
    sqb[tid]=dx*dx+dy*dy+dz*dz;
    dxb[tid]=dx; dyb[tid]=dy; dzb[tid]=dz;
  }
  { float4* wd = (float4*)wlds;
    wd[tid]=st0; wd[tid+512]=st1; wd[tid+1024]=st2; wd[tid+1536]=st3; wd[tid+2048]=st4; }
  __syncthreads();

  int rowb = 16*wl + l15;
  int s = sbuf[rowb], d = dbuf[rowb];
  float sqv = sqb[rowb];
  const short8* wfr = (const short8*)wlds;

  // ---- GEMM0 + exact fp32 epilogue, silu, trunc-split -> LDS ----
  #pragma unroll
  for(int mt=0;mt<4;mt++){
    short8 ah = wfr[(2*mt+0)*64+lane];
    short8 al = wfr[(2*mt+1)*64+lane];
    f32x4 c = {0.f,0.f,0.f,0.f};
    c = MFMA_BF16(ah, ebh, c);
    c = MFMA_BF16(ah, ebl, c);
    c = MFMA_BF16(al, ebh, c);
    float4 Ai = *(const float4*)(pa + (size_t)s*64 + mt*16 + q4*4);
    float4 Bi = *(const float4*)(pb + (size_t)d*64 + mt*16 + q4*4);
    float4 Wq = *(const float4*)(w1 + 256*64 + mt*16 + q4*4);
    float v0 = siluf(c[0] + Ai.x + Bi.x + sqv*Wq.x);
    float v1 = siluf(c[1] + Ai.y + Bi.y + sqv*Wq.y);
    float v2 = siluf(c[2] + Ai.z + Bi.z + sqv*Wq.z);
    float v3 = siluf(c[3] + Ai.w + Bi.w + sqv*Wq.w);
    unsigned h01,h23,l01,l23;
    split4(v0,v1,v2,v3,h01,h23,l01,l23);
    int mo = rowb*TSTR + mt*16 + q4*4;
    *(unsigned*)&tHi[mo]   = h01;
    *(unsigned*)&tHi[mo+2] = h23;
    *(unsigned*)&tLo[mo]   = l01;
    *(unsigned*)&tLo[mo+2] = l23;
  }
  // no barrier: wave reads only its own rows

  // ---- GEMM1: msg = silu(w2^T @ t + b2), repack trunc-split in place ----
  { short8 bh0 = ldB(tHi, rowb, q4*8);
    short8 bh1 = ldB(tHi, rowb, 32 + q4*8);
    short8 bl0 = ldB(tLo, rowb, q4*8);
    short8 bl1 = ldB(tLo, rowb, 32 + q4*8);
    #pragma unroll
    for(int mt=0;mt<4;mt++){
      short8 ah0 = wfr[(8+mt*4+0)*64+lane];
      short8 al0 = wfr[(8+mt*4+1)*64+lane];
      short8 ah1 = wfr[(8+mt*4+2)*64+lane];
      short8 al1 = wfr[(8+mt*4+3)*64+lane];
      f32x4 c = {0.f,0.f,0.f,0.f};
      c = MFMA_BF16(ah0,bh0,c); c = MFMA_BF16(ah0,bl0,c); c = MFMA_BF16(al0,bh0,c);
      c = MFMA_BF16(ah1,bh1,c); c = MFMA_BF16(ah1,bl1,c); c = MFMA_BF16(al1,bh1,c);
      float4 bb = *(const float4*)(b2 + mt*16 + q4*4);
      float v0=siluf(c[0]+bb.x), v1=siluf(c[1]+bb.y), v2=siluf(c[2]+bb.z), v3=siluf(c[3]+bb.w);
      unsigned h01,h23,l01,l23;
      split4(v0,v1,v2,v3,h01,h23,l01,l23);
      int mo = rowb*TSTR + mt*16 + q4*4;
      *(unsigned*)&tHi[mo]   = h01;
      *(unsigned*)&tHi[mo+2] = h23;
      *(unsigned*)&tLo[mo]   = l01;
      *(unsigned*)&tLo[mo+2] = l23;
    } }

  // ---- GEMM2: xh = xw1^T @ msg; w = silu(xh)·xw2 + xb2; stream cvec ----
  { short8 mh0 = ldB(tHi, rowb, q4*8);
    short8 mh1 = ldB(tHi, rowb, 32 + q4*8);
    short8 ml0 = ldB(tLo, rowb, q4*8);
    short8 ml1 = ldB(tLo, rowb, 32 + q4*8);
    float part = 0.f;
    #pragma unroll
    for(int mt=0;mt<4;mt++){
      short8 ah0 = wfr[(24+mt*4+0)*64+lane];
      short8 al0 = wfr[(24+mt*4+1)*64+lane];
      short8 ah1 = wfr[(24+mt*4+2)*64+lane];
      short8 al1 = wfr[(24+mt*4+3)*64+lane];
      f32x4 c = {0.f,0.f,0.f,0.f};
      c = MFMA_BF16(ah0,mh0,c); c = MFMA_BF16(ah0,ml0,c); c = MFMA_BF16(al0,mh0,c);
      c = MFMA_BF16(ah1,mh1,c); c = MFMA_BF16(ah1,ml1,c); c = MFMA_BF16(al1,mh1,c);
      float4 xb  = *(const float4*)(xb1 + mt*16 + q4*4);
      float4 wv4 = *(const float4*)(xw2 + mt*16 + q4*4);
      part += siluf(c[0]+xb.x)*wv4.x + siluf(c[1]+xb.y)*wv4.y
            + siluf(c[2]+xb.z)*wv4.z + siluf(c[3]+xb.w)*wv4.w;
    }
    part += __shfl_xor(part,16);
    part += __shfl_xor(part,32);
    int pw = p0 + rowb;
    if (q4==0 && pw < NE){
      float wv = part + xb2[0];
      cvec[pw] = make_float4(dxb[rowb]*wv, dyb[rowb]*wv, dzb[rowb]*wv, 0.f);
    }
  }
  __syncthreads();                 // msg final (all rows)

  // ---- fused segmented reduction over dst: 2 cols/thread, dword reads ----
  int pend = (p0+EB < NE) ? (p0+EB) : NE;
  int dfirst = sd[p0].y;
  int dlast  = sd[pend-1].y;
  int jj = (tid&31)*2, slot = tid>>5;
  for (int n=dfirst+slot; n<=dlast; n+=16){
    int rs0 = roff_dst[n], re0 = roff_dst[n+1];
    int rs = (rs0 > p0)   ? rs0 : p0;
    int re = (re0 < pend) ? re0 : pend;
    rs -= p0; re -= p0;
    if (re > rs){
      float s0=0.f, s1=0.f;
      for (int r=rs; r<re; r++){
        unsigned dh = *(const unsigned*)&tHi[r*TSTR+jj];
        unsigned dl = *(const unsigned*)&tLo[r*TSTR+jj];
        s0 += __uint_as_float(dh<<16) + __uint_as_float(dl<<16);
        s1 += __uint_as_float(dh&0xFFFF0000u) + __uint_as_float(dl&0xFFFF0000u);
      }
      if (rs0 >= p0 && re0 <= pend){
        float2 o = make_float2(s0,s1);
        *(float2*)&agg[(size_t)n*64+jj] = o;
      } else {
        atomicAdd(&agg[(size_t)n*64+jj], s0);
        atomicAdd(&agg[(size_t)n*64+jj+1], s1);
      }
    }
  }
}

// ==== MFMA k_node + fused coordC + fused next-layer pre ====
// coordC: this block's 32 nodes gather cvec[slist[...]] (8 threads/node) and
// update x directly — latency hidden under the GEMM phases of other waves.
__global__ void __launch_bounds__(256)
k_nodeM(const float* __restrict__ agg,
        const int* __restrict__ roff_src, const int* __restrict__ slist,
        const float4* __restrict__ cvec,
        const float* __restrict__ cntinv,
        const float* __restrict__ hb1, const float* __restrict__ hb2,
        const float* __restrict__ lng, const float* __restrict__ lnb,
        const unsigned short* __restrict__ nbase,
        const unsigned short* __restrict__ nextpre, const float* __restrict__ nb1,
        float* __restrict__ h, float* __restrict__ x,
        float* __restrict__ pa, float* __restrict__ pb){
  __shared__ float hsf[32][132];
  __shared__ unsigned short cHi[32*194], cLo[32*194];
  __shared__ unsigned short t2Hi[32*130], t2Lo[32*130];
  __shared__ float psA[32][8], psB[32][8];
  __shared__ float mu_s[32], rs_s[32];
  int tid=threadIdx.x;
  int g0=blockIdx.x*32;
  { int n=tid>>3, c0=(tid&7)*16;
    int gn=g0+n; if(gn>=NN) gn=NN-1;
    const float* src=h+(size_t)gn*128+c0;
    #pragma unroll
    for(int q=0;q<4;q++){
      float4 v=*(const float4*)(src+q*4);
      *(float4*)&hsf[n][c0+q*4]=v;
      unsigned h01,h23,l01,l23;
      split4(v.x,v.y,v.z,v.w,h01,h23,l01,l23);
      int o=n*194+c0+q*4;
      *(unsigned*)&cHi[o]=h01; *(unsigned*)&cHi[o+2]=h23;
      *(unsigned*)&cLo[o]=l01; *(unsigned*)&cLo[o+2]=l23;
    }
    float ci=cntinv[gn];
    int ca=(tid&7)*8;
    const float* srca=agg+(size_t)gn*64+ca;
    #pragma unroll
    for(int q=0;q<2;q++){
      float4 v=*(const float4*)(srca+q*4);
      unsigned h01,h23,l01,l23;
      split4(v.x*ci,v.y*ci,v.z*ci,v.w*ci,h01,h23,l01,l23);
      int o=n*194+128+ca+q*4;
      *(unsigned*)&cHi[o]=h01; *(unsigned*)&cHi[o+2]=h23;
      *(unsigned*)&cLo[o]=l01; *(unsigned*)&cLo[o+2]=l23;
    } }
  // ---- fused coordC: gather cvec over out-edges of this block's nodes ----
  { int n = tid>>3, sub = tid&7;
    int gn = g0+n;
    if (gn < NN){
      int s0 = roff_src[gn], e0 = roff_src[gn+1];
      float a0=0.f, a1=0.f, a2=0.f;
      for (int p=s0+sub; p<e0; p+=8){
        float4 c = cvec[slist[p]];
        a0 += c.x; a1 += c.y; a2 += c.z;
      }
      a0 += __shfl_xor(a0,1); a1 += __shfl_xor(a1,1); a2 += __shfl_xor(a2,1);
      a0 += __shfl_xor(a0,2); a1 += __shfl_xor(a1,2); a2 += __shfl_xor(a2,2);
      a0 += __shfl_xor(a0,4); a1 += __shfl_xor(a1,4); a2 += __shfl_xor(a2,4);
      if (sub==0){
        float ci = cntinv[gn];
        x[gn*3+0]+=a0*ci; x[gn*3+1]+=a1*ci; x[gn*3+2]+=a2*ci;
      }
    } }
  __syncthreads();
  int wl=tid>>6, lane=tid&63, q4=lane>>4, l15=lane&15;
  const short8* f1 = (const short8*)(nbase + 32768);
  const short8* f2 = (const short8*)(nbase + 81920);
  // GEMM1: t = silu(cat @ hw1 + hb1), K=192
  #pragma unroll
  for(int mi=0;mi<2;mi++){
    int mt=wl+mi*4;
    short8 A[6][2];
    #pragma unroll
    for(int kt=0;kt<6;kt++){
      A[kt][0]=f1[(size_t)((mt*6+kt)*2+0)*64+lane];
      A[kt][1]=f1[(size_t)((mt*6+kt)*2+1)*64+lane];
    }
    f32x4 acc0={0.f,0.f,0.f,0.f}, acc1=acc0;
    #pragma unroll
    for(int kt=0;kt<6;kt++){
      short8 bh0=ldBs(cHi, l15,    kt*32+q4*8, 194);
      short8 bl0=ldBs(cLo, l15,    kt*32+q4*8, 194);
      short8 bh1=ldBs(cHi, 16+l15, kt*32+q4*8, 194);
      short8 bl1=ldBs(cLo, 16+l15, kt*32+q4*8, 194);
      acc0=MFMA_BF16(A[kt][0],bh0,acc0); acc0=MFMA_BF16(A[kt][0],bl0,acc0); acc0=MFMA_BF16(A[kt][1],bh0,acc0);
      acc1=MFMA_BF16(A[kt][0],bh1,acc1); acc1=MFMA_BF16(A[kt][0],bl1,acc1); acc1=MFMA_BF16(A[kt][1],bh1,acc1);
    }
    int m0=mt*16+q4*4;
    float4 bias=*(const float4*)(hb1+m0);
    #pragma unroll
    for(int nt=0;nt<2;nt++){
      f32x4 c = nt ? acc1 : acc0;
      int row=nt*16+l15;
      float v0=siluf(c[0]+bias.x), v1=siluf(c[1]+bias.y), v2=siluf(c[2]+bias.z), v3=siluf(c[3]+bias.w);
      unsigned h01,h23,l01,l23;
      split4(v0,v1,v2,v3,h01,h23,l01,l23);
      int mo=row*130+m0;
      *(unsigned*)&t2Hi[mo]=h01; *(unsigned*)&t2Hi[mo+2]=h23;
      *(unsigned*)&t2Lo[mo]=l01; *(unsigned*)&t2Lo[mo+2]=l23;
    }
  }
  __syncthreads();
  // GEMM2: dh = t @ hw2 + hb2; hsf += dh
  #pragma unroll
  for(int mi=0;mi<2;mi++){
    int mt=wl+mi*4;
    short8 A[4][2];
    #pragma unroll
    for(int kt=0;kt<4;kt++){
      A[kt][0]=f2[(size_t)((mt*4+kt)*2+0)*64+lane];
      A[kt][1]=f2[(size_t)((mt*4+kt)*2+1)*64+lane];
    }
    f32x4 acc0={0.f,0.f,0.f,0.f}, acc1=acc0;
    #pragma unroll
    for(int kt=0;kt<4;kt++){
      short8 bh0=ldBs(t2Hi, l15,    kt*32+q4*8, 130);
      short8 bl0=ldBs(t2Lo, l15,    kt*32+q4*8, 130);
      short8 bh1=ldBs(t2Hi, 16+l15, kt*32+q4*8, 130);
      short8 bl1=ldBs(t2Lo, 16+l15, kt*32+q4*8, 130);
      acc0=MFMA_BF16(A[kt][0],bh0,acc0); acc0=MFMA_BF16(A[kt][0],bl0,acc0); acc0=MFMA_BF16(A[kt][1],bh0,acc0);
      acc1=MFMA_BF16(A[kt][0],bh1,acc1); acc1=MFMA_BF16(A[kt][0],bl1,acc1); acc1=MFMA_BF16(A[kt][1],bh1,acc1);
    }
    int m0=mt*16+q4*4;
    float4 bias=*(const float4*)(hb2+m0);
    #pragma unroll
    for(int nt=0;nt<2;nt++){
      f32x4 c = nt ? acc1 : acc0;
      int row=nt*16+l15;
      hsf[row][m0+0]+=c[0]+bias.x;
      hsf[row][m0+1]+=c[1]+bias.y;
      hsf[row][m0+2]+=c[2]+bias.z;
      hsf[row][m0+3]+=c[3]+bias.w;
    }
  }
  __syncthreads();
  // LayerNorm (fp32, exact)
  { int rid=tid>>3, sub=tid&7;
    float sm=0.f, ss=0.f;
    #pragma unroll
    for(int i=0;i<16;i++){ float v=hsf[rid][sub*16+i]; sm+=v; ss+=v*v; }
    psA[rid][sub]=sm; psB[rid][sub]=ss; }
  __syncthreads();
  { int rid=tid>>3, sub=tid&7;
    if(sub==0){
      float sm=0.f, ss=0.f;
      #pragma unroll
      for(int i=0;i<8;i++){ sm+=psA[rid][i]; ss+=psB[rid][i]; }
      float mu=sm*(1.0f/128.0f);
      float var=ss*(1.0f/128.0f)-mu*mu;
      mu_s[rid]=mu; rs_s[rid]=rsqrtf(fmaxf(var,0.0f)+1e-5f);
    } }
  __syncthreads();
  // LN write phase: store h AND re-split normalized tile into cHi/cLo (stride 130)
  { int rid=tid>>3, sub=tid&7;
    int gn=g0+rid;
    bool ok = gn<NN;
    float mu=mu_s[rid], rs=rs_s[rid];
    int c0=sub*16;
    #pragma unroll
    for(int q=0;q<4;q++){
      float4 g4=*(const float4*)(lng+c0+q*4);
      float4 b4=*(const float4*)(lnb+c0+q*4);
      float4 o;
      o.x=(hsf[rid][c0+q*4+0]-mu)*rs*g4.x+b4.x;
      o.y=(hsf[rid][c0+q*4+1]-mu)*rs*g4.y+b4.y;
      o.z=(hsf[rid][c0+q*4+2]-mu)*rs*g4.z+b4.z;
      o.w=(hsf[rid][c0+q*4+3]-mu)*rs*g4.w+b4.w;
      if(ok) *(float4*)(h+(size_t)gn*128+c0+q*4)=o;
      if(nextpre){
        unsigned h01,h23,l01,l23;
        split4(o.x,o.y,o.z,o.w,h01,h23,l01,l23);
        int oo=rid*130+c0+q*4;
        *(unsigned*)&cHi[oo]=h01; *(unsigned*)&cHi[oo+2]=h23;
        *(unsigned*)&cLo[oo]=l01; *(unsigned*)&cLo[oo+2]=l23;
      }
    } }
  // ---- fused next-layer pre: pa|pb = h_new @ [W1_pa|W1_pb] (+nb1 on pa) ----
  if(nextpre){
    __syncthreads();
    const short8* fr = (const short8*)nextpre;
    #pragma unroll
    for(int mi=0;mi<2;mi++){
      int mt = wl + mi*4;
      short8 A[4][2];
      #pragma unroll
      for(int kt=0;kt<4;kt++){
        A[kt][0]=fr[(size_t)((mt*4+kt)*2+0)*64+lane];
        A[kt][1]=fr[(size_t)((mt*4+kt)*2+1)*64+lane];
      }
      f32x4 acc0={0.f,0.f,0.f,0.f}, acc1=acc0;
      #pragma unroll
      for(int kt=0;kt<4;kt++){
        short8 bh0=ldBs(cHi, l15,    kt*32+q4*8, 130);
        short8 bl0=ldBs(cLo, l15,    kt*32+q4*8, 130);
        short8 bh1=ldBs(cHi, 16+l15, kt*32+q4*8, 130);
        short8 bl1=ldBs(cLo, 16+l15, kt*32+q4*8, 130);
        acc0=MFMA_BF16(A[kt][0],bh0,acc0); acc0=MFMA_BF16(A[kt][0],bl0,acc0); acc0=MFMA_BF16(A[kt][1],bh0,acc0);
        acc1=MFMA_BF16(A[kt][0],bh1,acc1); acc1=MFMA_BF16(A[kt][0],bl1,acc1); acc1=MFMA_BF16(A[kt][1],bh1,acc1);
      }
      int m0=mt*16+q4*4;
      float4 bias = (mt<4) ? *(const float4*)(nb1+m0) : make_float4(0,0,0,0);
      #pragma unroll
      for(int nt=0;nt<2;nt++){
        f32x4 c = nt ? acc1 : acc0;
        int node=g0+nt*16+l15;
        if(node<NN){
          float4 o = make_float4(c[0]+bias.x, c[1]+bias.y, c[2]+bias.z, c[3]+bias.w);
          if (mt<4) *(float4*)(pa+(size_t)node*64+m0)=o;
          else      *(float4*)(pb+(size_t)node*64+(m0-64))=o;
        }
      }
    }
  }
}

// ---- readout (unchanged) ----
__device__ __forceinline__ int lowerb(const int* a, int n, int v){
  int lo=0, hi=n;
  while(lo<hi){ int mid=(lo+hi)>>1; if(a[mid]<v) lo=mid+1; else hi=mid; }
  return lo;
}

__global__ void k_readout(const int* __restrict__ batch, const float* __restrict__ h,
                          const float* __restrict__ w1, const float* __restrict__ b1,
                          const float* __restrict__ w2, const float* __restrict__ b2,
                          const float* __restrict__ w3, const float* __restrict__ b3,
                          float* __restrict__ out){
  int g = blockIdx.x;
  int wl = threadIdx.x>>6, lane = threadIdx.x&63;
  __shared__ float part[4][128];
  __shared__ float gh[128];
  __shared__ float r1[128];
  __shared__ float r2[64];
  int start = lowerb(batch, NN, g);
  int end   = lowerb(batch, NN, g+1);
  float s0=0.f, s1=0.f;
  for(int n=start+wl; n<end; n+=4){
    s0 += h[(size_t)n*128+2*lane];
    s1 += h[(size_t)n*128+2*lane+1];
  }
  part[wl][2*lane]=s0; part[wl][2*lane+1]=s1;
  __syncthreads();
  float ci = 1.0f/fmaxf((float)(end-start),1.0f);
  if(wl==0){
    gh[2*lane]   = (part[0][2*lane]+part[1][2*lane]+part[2][2*lane]+part[3][2*lane])*ci;
    gh[2*lane+1] = (part[0][2*lane+1]+part[1][2*lane+1]+part[2][2*lane+1]+part[3][2*lane+1])*ci;
  }
  __syncthreads();
  if(wl==0){
    float a0=b1[2*lane], a1=b1[2*lane+1];
    for(int k=0;k<128;k++){
      float m=gh[k];
      float2 w=((const float2*)(w1+k*128))[lane];
      a0+=m*w.x; a1+=m*w.y;
    }
    r1[2*lane]=siluf(a0); r1[2*lane+1]=siluf(a1);
  }
  __syncthreads();
  if(wl==0){
    float b=b2[lane];
    for(int k=0;k<128;k++) b += r1[k]*w2[k*64+lane];
    r2[lane]=siluf(b);
  }
  __syncthreads();
  if(wl==0 && lane<2){
    float o=b3[lane];
    for(int k=0;k<64;k++) o += r2[k]*w3[k*2+lane];
    out[g*2+lane]=o;
  }
}

extern "C" void kernel_launch(void* const* d_in, const int* in_sizes, int n_in,
                              void* d_out, int out_size, void* d_ws, size_t ws_size,
                              hipStream_t stream){
  const float* nf     = (const float*)d_in[0];
  const float* coords = (const float*)d_in[1];
  const int*   ei     = (const int*)d_in[2];
  const float* ef     = (const float*)d_in[3];
  const int*   batch  = (const int*)d_in[4];

  const float* enc_w1 = (const float*)d_in[5];
  const float* enc_b1 = (const float*)d_in[6];
  const float* enc_w2 = (const float*)d_in[7];
  const float* enc_b2 = (const float*)d_in[8];
  const float* pe_w1  = (const float*)d_in[9];
  const float* pe_b1  = (const float*)d_in[10];
  const float* pe_w2  = (const float*)d_in[11];
  const float* pe_b2  = (const float*)d_in[12];
  const float* ph_w1  = (const float*)d_in[13];
  const float* ph_b1  = (const float*)d_in[14];
  const float* ph_w2  = (const float*)d_in[15];
  const float* ph_b2  = (const float*)d_in[16];
  const float* px_w1  = (const float*)d_in[17];
  const float* px_b1  = (const float*)d_in[18];
  const float* px_w2  = (const float*)d_in[19];
  const float* px_b2  = (const float*)d_in[20];
  const float* ln_g   = (const float*)d_in[21];
  const float* ln_b   = (const float*)d_in[22];
  const float* ro_w1  = (const float*)d_in[23];
  const float* ro_b1  = (const float*)d_in[24];
  const float* ro_w2  = (const float*)d_in[25];
  const float* ro_b2  = (const float*)d_in[26];
  const float* ro_w3  = (const float*)d_in[27];
  const float* ro_b3  = (const float*)d_in[28];

  char* wsb = (char*)d_ws;
  size_t off = 0;
  auto alloc_f = [&](size_t nfl)->float*{ float* p=(float*)(wsb+off); off+=nfl*4; return p; };
  auto alloc_i = [&](size_t nin)->int*  { int*   p=(int*)(wsb+off);   off+=nin*4; return p; };

  float* h      = alloc_f((size_t)NN*128);
  float* x      = alloc_f((size_t)NN*3);
  float* agg    = alloc_f((size_t)NN*64);
  float* cntinv = alloc_f(NN);
  float* pa     = alloc_f((size_t)NN*64);
  float* pb     = alloc_f((size_t)NN*64);
  float4* cvec  = (float4*)alloc_f((size_t)NE*4);        // 16 MB streaming per layer
  unsigned short* efb = (unsigned short*)alloc_f((size_t)NE*16 + 2048); // 64 MB + tail pad
  int2*  sd_s   = (int2*)alloc_i((size_t)NE*2);
  unsigned short* wblob = (unsigned short*)alloc_i((size_t)NL*40*512/2);   // 245,760 B
  unsigned short* nblob = (unsigned short*)alloc_i((size_t)NL*224*512/2);  // 1,376,256 B
  int* roff_dst = alloc_i(NN+1);
  int* roff_src = alloc_i(NN+1);
  int* dlist    = alloc_i(NE);
  int* slist    = alloc_i(NE);
  int* bsum     = alloc_i(256);
  int* bbase    = alloc_i(256);
  int* cnt_dst  = alloc_i(NN);   // cnt_dst..cur_src contiguous -> one memset
  int* cnt_src  = alloc_i(NN);
  int* cur_dst  = alloc_i(NN);
  int* cur_src  = alloc_i(NN);

  hipMemsetAsync(cnt_dst, 0, (size_t)4*NN*sizeof(int), stream);
  k_degrees<<<(NE+255)/256,256,0,stream>>>(ei, cnt_dst, cnt_src);
  k_scan1<<<NB_SCAN,256,0,stream>>>(cnt_dst, roff_dst, bsum);
  k_scan2<<<1,256,0,stream>>>(bsum, bbase, roff_dst);
  k_scan3<<<NB_SCAN,256,0,stream>>>(roff_dst, bbase);
  k_scan1<<<NB_SCAN,256,0,stream>>>(cnt_src, roff_src, bsum);
  k_scan2<<<1,256,0,stream>>>(bsum, bbase, roff_src);
  k_scan3<<<NB_SCAN,256,0,stream>>>(roff_src, bbase);
  k_fill<<<(NE+255)/256,256,0,stream>>>(ei, roff_dst, roff_src, cur_dst, cur_src, dlist, slist);
  k_gather<<<(NE+255)/256,256,0,stream>>>(ei, ef, dlist, sd_s, efb);
  k_prep<<<(NN+255)/256,256,0,stream>>>(coords, cnt_dst, x, cntinv);
  k_wprep<<<(NL*40*64+255)/256,256,0,stream>>>(pe_w1, pe_w2, px_w1, wblob);
  k_wprep2<<<(NL*224*64+255)/256,256,0,stream>>>(pe_w1, ph_w1, ph_w2, nblob);
  k_encoder<<<(NN+31)/32,256,0,stream>>>(nf, enc_w1, enc_b1, enc_w2, enc_b2, h);

  int G  = (NE+EB-1)/EB;
  int G8 = ((G+7)/8)*8;

  // layer-0 pre (encoder output -> pa/pb); later layers fused into k_nodeM
  k_preM<<<(NN+31)/32,256,0,stream>>>(h, pe_b1, nblob, pa, pb);

  for(int l=0;l<NL;l++){
    const unsigned short* nbl = nblob + (size_t)l*224*512;
    hipMemsetAsync(agg, 0, (size_t)NN*64*sizeof(float), stream);
    k_edge2<<<G8,512,0,stream>>>(sd_s, efb, x, pa, pb, roff_dst,
        pe_w1+(size_t)l*273*64,
        pe_b2+l*64,
        px_b1+l*64,
        px_w2+l*64, px_b2+l,
        wblob + (size_t)l*40*512,
        agg, cvec);
    const unsigned short* nxt = (l+1<NL) ? (nblob + (size_t)(l+1)*224*512) : (const unsigned short*)nullptr;
    const float* nb1 = (l+1<NL) ? (pe_b1 + (size_t)(l+1)*64) : pe_b1;
    k_nodeM<<<(NN+31)/32,256,0,stream>>>(agg, roff_src, slist, cvec, cntinv,
        ph_b1+l*128, ph_b2+l*128,
        ln_g+l*128, ln_b+l*128, nbl,
        nxt, nb1, h, x, pa, pb);
  }

  k_readout<<<NG,256,0,stream>>>(batch, h,
      ro_w1, ro_b1, ro_w2, ro_b2, ro_w3, ro_b3, (float*)d_out);
}